// Round 16
// baseline (633.043 us; speedup 1.0000x reference)
//
#include <hip/hip_runtime.h>

// ---------------------------------------------------------------------------
// MLA forward, MI355X (gfx950). FP16 MFMA, f32 accumulate.
// SEQ=4096 EMBED=2048 H=16 QLR=512 KVLR=512 RD=64 VD=128 KD=192
// Round 16: deconfounded TLP test. r13/r15 fattn with single-buffered K+V
//           (40 KB LDS -> 4 blocks/CU = 16 waves/CU, 2x r8) and
//           __launch_bounds__(256,4) (cap 128 >= measured 108 VGPR).
//           Stage latency exposed per block, hidden by cross-block TLP.
//           GEMMs / cvt_all / rope unchanged from r15.
// ---------------------------------------------------------------------------

#define SEQ   4096
#define EMBED 2048
#define NHEAD 16
#define QLR   512
#define KVLR  512
#define RD    64
#define VD    128
#define KDIM  192

typedef __attribute__((ext_vector_type(8)))  _Float16 half8;
typedef __attribute__((ext_vector_type(4)))  _Float16 half4;
typedef __attribute__((ext_vector_type(4)))  float    f32x4;
typedef __attribute__((ext_vector_type(16))) float    f32x16;
typedef __attribute__((ext_vector_type(2)))  unsigned int uint2v;
typedef __attribute__((ext_vector_type(4)))  unsigned int uint4v;

__device__ __forceinline__ void gload16(void* lds, const void* g) {
    __builtin_amdgcn_global_load_lds(
        (const __attribute__((address_space(1))) void*)g,
        (__attribute__((address_space(3))) void*)lds, 16, 0, 0);
}

__device__ __forceinline__ unsigned int pkh(float a, float b) {
    auto h = __builtin_amdgcn_cvt_pkrtz(a, b);   // __fp16 ext_vector(2)
    return __builtin_bit_cast(unsigned int, h);
}

__device__ __forceinline__ half8 cvt8(const float* p) {
    const float4 a = *reinterpret_cast<const float4*>(p);
    const float4 b = *reinterpret_cast<const float4*>(p + 4);
    half8 r;
    r[0] = (_Float16)a.x; r[1] = (_Float16)a.y; r[2] = (_Float16)a.z; r[3] = (_Float16)a.w;
    r[4] = (_Float16)b.x; r[5] = (_Float16)b.y; r[6] = (_Float16)b.z; r[7] = (_Float16)b.w;
    return r;
}

// ---------------- fused f32 -> f16 conversions (x, wdown, wqup, wkvu) ------
__global__ __launch_bounds__(256) void cvt_all(const float* __restrict__ x,
                                               const float* __restrict__ wqd,
                                               const float* __restrict__ wkvd,
                                               const float* __restrict__ wkr,
                                               const float* __restrict__ wqu,
                                               const float* __restrict__ wqr,
                                               const float* __restrict__ wkvu,
                                               _Float16* __restrict__ x_h,
                                               _Float16* __restrict__ wdownh,
                                               _Float16* __restrict__ wquph,
                                               _Float16* __restrict__ wkvuh)
{
    const int b = blockIdx.x;
    if (b < 4096) {
        const int i = b * 256 + threadIdx.x;
        reinterpret_cast<half8*>(x_h)[i] = cvt8(x + i * 8);
    } else if (b < 5248) {
        const int i = (b - 4096) * 256 + threadIdx.x;
        const int e = i * 8, row = e >> 11, col = e & 2047;
        const float* src = row < 512  ? wqd  + (size_t)row * 2048 + col
                         : row < 1024 ? wkvd + (size_t)(row - 512) * 2048 + col
                         : row < 1088 ? wkr  + (size_t)(row - 1024) * 2048 + col
                                      : nullptr;
        half8 r = {};
        if (src) r = cvt8(src);
        reinterpret_cast<half8*>(wdownh)[i] = r;
    } else if (b < 6016) {
        const int i = (b - 5248) * 256 + threadIdx.x;
        const int e = i * 8, row = e >> 9, col = e & 511;
        const float* src = row < 2048 ? wqu + (size_t)row * 512 + col
                                      : wqr + (size_t)(row - 2048) * 512 + col;
        reinterpret_cast<half8*>(wquph)[i] = cvt8(src);
    } else {
        const int i = (b - 6016) * 256 + threadIdx.x;
        reinterpret_cast<half8*>(wkvuh)[i] = cvt8(wkvu + i * 8);
    }
}

__global__ __launch_bounds__(256) void cvt_plain(const float* __restrict__ s,
                                                 _Float16* __restrict__ d, int n8) {
    const int i = blockIdx.x * 256 + threadIdx.x;
    if (i >= n8) return;
    reinterpret_cast<half8*>(d)[i] = cvt8(s + i * 8);
}

// ---------------------------------------------------------------------------
// f16 GEMM, m97 structure (r13 verbatim).
// ---------------------------------------------------------------------------
template <int EPI>
__global__ __launch_bounds__(256) void gemm_f16(const _Float16* __restrict__ A,
                                                const _Float16* __restrict__ B,
                                                _Float16* __restrict__ o0,
                                                _Float16* __restrict__ o1,
                                                _Float16* __restrict__ o2,
                                                float* __restrict__ of,
                                                int M, int N, int K)
{
    __shared__ _Float16 sA[128 * 64];
    __shared__ _Float16 sB[128 * 64];

    const int tid  = threadIdx.x;
    const int wid  = tid >> 6;
    const int lane = tid & 63;
    const int lr   = lane & 15;
    const int lg   = lane >> 4;
    const int row0 = blockIdx.y * 128;
    const int col0 = blockIdx.x * 128;
    const int war  = (wid >> 1) * 64;
    const int wac  = (wid & 1) * 64;

    const int sr = lane >> 3;
    const int sk = (lane & 7) * 8;
    const _Float16* Ab = A + (size_t)(row0 + wid * 8 + sr) * K + sk;
    const _Float16* Bb = B + (size_t)(col0 + wid * 8 + sr) * K + sk;

    f32x4 acc[4][4] = {};

    for (int k0 = 0; k0 < K; k0 += 64) {
#pragma unroll
        for (int i = 0; i < 4; ++i) {
            const int c = i * 4 + wid;
            gload16((char*)sA + c * 1024, Ab + (size_t)i * 32 * K + k0);
            gload16((char*)sB + c * 1024, Bb + (size_t)i * 32 * K + k0);
        }
        __syncthreads();

#pragma unroll
        for (int kk = 0; kk < 64; kk += 32) {
            half8 a[4], b[4];
#pragma unroll
            for (int i = 0; i < 4; ++i)
                a[i] = *reinterpret_cast<const half8*>(&sA[(war + i * 16 + lr) * 64 + kk + lg * 8]);
#pragma unroll
            for (int j = 0; j < 4; ++j)
                b[j] = *reinterpret_cast<const half8*>(&sB[(wac + j * 16 + lr) * 64 + kk + lg * 8]);
            __builtin_amdgcn_s_setprio(1);
#pragma unroll
            for (int i = 0; i < 4; ++i)
#pragma unroll
                for (int j = 0; j < 4; ++j)
                    acc[i][j] = __builtin_amdgcn_mfma_f32_16x16x32_f16(a[i], b[j], acc[i][j], 0, 0, 0);
            __builtin_amdgcn_s_setprio(0);
        }
        __syncthreads();
    }

#pragma unroll
    for (int i = 0; i < 4; ++i)
#pragma unroll
        for (int j = 0; j < 4; ++j) {
            const int grow0 = row0 + war + i * 16 + lg * 4;
            const int gcol  = col0 + wac + j * 16 + lr;
            if constexpr (EPI == 2) {
                if (gcol >= 2048) {
                    half4 pv;
#pragma unroll
                    for (int r = 0; r < 4; ++r) pv[r] = (_Float16)acc[i][j][r];
                    *reinterpret_cast<half4*>(&o1[(size_t)(gcol - 2048) * SEQ + grow0]) = pv;
                    continue;
                }
            }
#pragma unroll
            for (int r = 0; r < 4; ++r) {
                const int grow = grow0 + r;
                const float v = acc[i][j][r];
                if constexpr (EPI == 0) {
                    if (gcol < 512)       o0[(size_t)grow * 512 + gcol] = (_Float16)v;
                    else if (gcol < 1024) o1[(size_t)grow * 512 + gcol - 512] = (_Float16)v;
                    else if (gcol < 1088) o2[(size_t)grow * 64 + gcol - 1024] = (_Float16)v;
                } else if constexpr (EPI == 1) {
                    if (gcol < 2048)
                        o0[(size_t)grow * (NHEAD * KDIM) + (gcol >> 7) * KDIM + (gcol & 127)] = (_Float16)v;
                    else {
                        const int c = gcol - 2048;
                        o0[(size_t)grow * (NHEAD * KDIM) + (c >> 6) * KDIM + VD + (c & 63)] = (_Float16)v;
                    }
                } else if constexpr (EPI == 2) {
                    o0[((size_t)(gcol >> 7) * SEQ + grow) * KDIM + (gcol & 127)] = (_Float16)v;
                } else {
                    of[(size_t)grow * N + gcol] = v;
                }
            }
        }
}

// ---------------------------------------------------------------------------
// RoPE (standalone, r13 verbatim).
// ---------------------------------------------------------------------------
__global__ __launch_bounds__(256) void rope_kernel(_Float16* __restrict__ qf,
                                                   _Float16* __restrict__ kf,
                                                   const _Float16* __restrict__ ktmp)
{
    __shared__ float s_sin[32], s_cos[32];
    const int s   = blockIdx.x;
    const int tid = threadIdx.x;
    if (tid < 32) {
        const double inv = exp(-(double)tid * (log(10000.0) / 32.0));
        const double ang = (double)s * inv;
        s_sin[tid] = (float)sin(ang);
        s_cos[tid] = (float)cos(ang);
    }
    __syncthreads();

    for (int p = tid; p < NHEAD * 32; p += 256) {
        const int h = p >> 5, i = p & 31;
        const size_t base = (size_t)s * (NHEAD * KDIM) + h * KDIM + VD;
        const float x1 = (float)qf[base + i];
        const float x2 = (float)qf[base + 32 + i];
        const float cs = s_cos[i], sn = s_sin[i];
        qf[base + i]      = (_Float16)(x1 * cs - x2 * sn);
        qf[base + 32 + i] = (_Float16)(x2 * cs + x1 * sn);
    }
    if (tid < 32) {
        const int i = tid;
        const float x1 = (float)ktmp[(size_t)s * RD + i];
        const float x2 = (float)ktmp[(size_t)s * RD + 32 + i];
        const float cs = s_cos[i], sn = s_sin[i];
        const _Float16 r1 = (_Float16)(x1 * cs - x2 * sn);
        const _Float16 r2 = (_Float16)(x2 * cs + x1 * sn);
#pragma unroll
        for (int h = 0; h < NHEAD; ++h) {
            const size_t base = ((size_t)h * SEQ + s) * KDIM + VD;
            kf[base + i]      = r1;
            kf[base + 32 + i] = r2;
        }
    }
}

// ---------------------------------------------------------------------------
// Causal flash attention, TLP regime (deconfounded):
// 256 threads (4 waves), 128 q-cols/block (32/wave), KV step 64.
// K (24 KB) + V (16 KB) SINGLE-buffered -> 40 KB -> 4 blocks/CU
// (16 waves/CU, 4 waves/SIMD; VGPR cap 128 via launch_bounds(256,4),
// measured need 108 -> no spill). Per step:
//   bar(stage complete) -> QK -> softmax -> pack -> PV -> bar(reads done)
//   -> issue K[t+1], V[t+1].
// Stage latency exposed per block, hidden by 3 other resident blocks.
// All-register math identical to r8/r13.
// ---------------------------------------------------------------------------
__global__ __launch_bounds__(256, 4) void fattn(const _Float16* __restrict__ qf,
                                                const _Float16* __restrict__ kf,
                                                const _Float16* __restrict__ vT,
                                                _Float16* __restrict__ attn)
{
    __shared__ _Float16 sK[64 * 192];   // 24 KB
    __shared__ _Float16 sV[128 * 64];   // 16 KB

    const int idx = blockIdx.x;
    const int h   = idx & 15;
    const int j   = idx >> 4;                              // 0..31
    const int qt  = (j < 16) ? (31 - 2 * j) : (2 * (j - 16));
    const int q0  = qt * 128;

    const int tid  = threadIdx.x;
    const int wid  = tid >> 6;
    const int lane = tid & 63;
    const int l31  = lane & 31;
    const int h5   = lane >> 5;
    const int x7   = l31 & 7;
    const int qg   = q0 + wid * 32 + l31;
    const int q0w  = q0 + wid * 32;

    const float scale = 0.0721687836487032f;   // 1/sqrt(192)

    const _Float16* ksrc[6];
    int klds[6];
#pragma unroll
    for (int i = 0; i < 6; ++i) {
        const int c   = wid * 6 + i;
        const int gi  = c * 64 + lane;
        const int row = gi / 24;
        const int g   = gi % 24;
        ksrc[i] = kf + ((size_t)h * SEQ + row) * KDIM + ((g ^ (row & 7)) << 3);
        klds[i] = c * 1024;
    }
    const _Float16* vsrc[4];
    int vlds[4];
#pragma unroll
    for (int i = 0; i < 4; ++i) {
        const int c = wid * 4 + i;
        const int d = c * 8 + (lane >> 3);
        vsrc[i] = vT + ((size_t)h * VD + d) * SEQ + (((lane & 7) ^ (lane >> 3)) << 3);
        vlds[i] = c * 1024;
    }

    half8 qfr[12];
    {
        const _Float16* qb_ = qf + (size_t)qg * (NHEAD * KDIM) + h * KDIM + h5 * 8;
#pragma unroll
        for (int ks = 0; ks < 12; ++ks)
            qfr[ks] = *reinterpret_cast<const half8*>(qb_ + ks * 16);
    }

    f32x16 o0 = {}, o1 = {}, o2 = {}, o3 = {};
    float m_ = -1e30f, l_ = 0.0f;

    const int nt = 2 * qt + 2;

    // prologue: stage tile 0
#pragma unroll
    for (int i = 0; i < 6; ++i) gload16((char*)sK + klds[i], ksrc[i]);
#pragma unroll
    for (int i = 0; i < 4; ++i) gload16((char*)sV + vlds[i], vsrc[i]);

    for (int t = 0; t < nt; ++t) {
        const int j0 = t * 64;

        // barrier #1: stage complete (syncthreads drains vmcnt)
        __syncthreads();

        // ---- S^T = K · Q ----
        f32x16 s0 = {}, s1 = {};
        {
            const char* kb = (const char*)sK;
            __builtin_amdgcn_s_setprio(1);
#pragma unroll
            for (int ks = 0; ks < 12; ++ks) {
                const int go = ((ks * 2 + h5) ^ x7) << 4;
                const half8 ka = *reinterpret_cast<const half8*>(kb + l31 * 384 + go);
                const half8 kc = *reinterpret_cast<const half8*>(kb + (32 + l31) * 384 + go);
                s0 = __builtin_amdgcn_mfma_f32_32x32x16_f16(ka, qfr[ks], s0, 0, 0, 0);
                s1 = __builtin_amdgcn_mfma_f32_32x32x16_f16(kc, qfr[ks], s1, 0, 0, 0);
            }
            __builtin_amdgcn_s_setprio(0);
        }

        // ---- scale + causal mask ----
#pragma unroll
        for (int m = 0; m < 16; ++m) { s0[m] *= scale; s1[m] *= scale; }
        if (j0 + 63 > q0w) {
#pragma unroll
            for (int m = 0; m < 16; ++m) {
                const int kv = j0 + (m & 3) + 8 * (m >> 2) + 4 * h5;
                if (kv > qg)      s0[m] = -3.0e38f;
                if (kv + 32 > qg) s1[m] = -3.0e38f;
            }
        }

        // ---- row max ----
        float mx = s0[0];
#pragma unroll
        for (int m = 1; m < 16; ++m) mx = fmaxf(mx, s0[m]);
#pragma unroll
        for (int m = 0; m < 16; ++m) mx = fmaxf(mx, s1[m]);
        mx = fmaxf(mx, __shfl_xor(mx, 32, 64));

        // ---- defer-max online softmax ----
        if (!__all(mx - m_ <= 8.0f)) {
            const float mn = fmaxf(m_, mx);
            const float alpha = __expf(m_ - mn);
            m_ = mn;
            l_ *= alpha;
#pragma unroll
            for (int m = 0; m < 16; ++m) {
                o0[m] *= alpha; o1[m] *= alpha; o2[m] *= alpha; o3[m] *= alpha;
            }
        }
        float rs = 0.0f;
#pragma unroll
        for (int m = 0; m < 16; ++m) { const float p = __expf(s0[m] - m_); s0[m] = p; rs += p; }
#pragma unroll
        for (int m = 0; m < 16; ++m) { const float p = __expf(s1[m] - m_); s1[m] = p; rs += p; }
        rs += __shfl_xor(rs, 32, 64);
        l_ += rs;

        // ---- assemble P B-frags ----
        half8 pb0, pb1, pb2, pb3;
        {
            unsigned int x, x2, y, y2;
            x  = pkh(s0[0], s0[1]);  x2 = pkh(s0[2], s0[3]);
            y  = pkh(s0[4], s0[5]);  y2 = pkh(s0[6], s0[7]);
            uint2v r1 = __builtin_amdgcn_permlane32_swap(x, y, false, false);
            uint2v r2 = __builtin_amdgcn_permlane32_swap(x2, y2, false, false);
            { uint4v u = { r1[0], r2[0], r1[1], r2[1] }; pb0 = __builtin_bit_cast(half8, u); }
            x  = pkh(s0[8], s0[9]);  x2 = pkh(s0[10], s0[11]);
            y  = pkh(s0[12], s0[13]); y2 = pkh(s0[14], s0[15]);
            r1 = __builtin_amdgcn_permlane32_swap(x, y, false, false);
            r2 = __builtin_amdgcn_permlane32_swap(x2, y2, false, false);
            { uint4v u = { r1[0], r2[0], r1[1], r2[1] }; pb1 = __builtin_bit_cast(half8, u); }
            x  = pkh(s1[0], s1[1]);  x2 = pkh(s1[2], s1[3]);
            y  = pkh(s1[4], s1[5]);  y2 = pkh(s1[6], s1[7]);
            r1 = __builtin_amdgcn_permlane32_swap(x, y, false, false);
            r2 = __builtin_amdgcn_permlane32_swap(x2, y2, false, false);
            { uint4v u = { r1[0], r2[0], r1[1], r2[1] }; pb2 = __builtin_bit_cast(half8, u); }
            x  = pkh(s1[8], s1[9]);  x2 = pkh(s1[10], s1[11]);
            y  = pkh(s1[12], s1[13]); y2 = pkh(s1[14], s1[15]);
            r1 = __builtin_amdgcn_permlane32_swap(x, y, false, false);
            r2 = __builtin_amdgcn_permlane32_swap(x2, y2, false, false);
            { uint4v u = { r1[0], r2[0], r1[1], r2[1] }; pb3 = __builtin_bit_cast(half8, u); }
        }

        // ---- O^T += V^T · P ----
        {
            const char* vbse = (const char*)sV;
            __builtin_amdgcn_s_setprio(1);
#pragma unroll
            for (int ks = 0; ks < 4; ++ks) {
                const int go = ((ks * 2 + h5) ^ x7) << 4;
                const half8 pbk = ks == 0 ? pb0 : ks == 1 ? pb1 : ks == 2 ? pb2 : pb3;
                const half8 v0 = *reinterpret_cast<const half8*>(vbse + (l31)      * 128 + go);
                const half8 v1 = *reinterpret_cast<const half8*>(vbse + (32 + l31) * 128 + go);
                const half8 v2 = *reinterpret_cast<const half8*>(vbse + (64 + l31) * 128 + go);
                const half8 v3 = *reinterpret_cast<const half8*>(vbse + (96 + l31) * 128 + go);
                o0 = __builtin_amdgcn_mfma_f32_32x32x16_f16(v0, pbk, o0, 0, 0, 0);
                o1 = __builtin_amdgcn_mfma_f32_32x32x16_f16(v1, pbk, o1, 0, 0, 0);
                o2 = __builtin_amdgcn_mfma_f32_32x32x16_f16(v2, pbk, o2, 0, 0, 0);
                o3 = __builtin_amdgcn_mfma_f32_32x32x16_f16(v3, pbk, o3, 0, 0, 0);
            }
            __builtin_amdgcn_s_setprio(0);
        }

        // barrier #2: all reads done -> safe to overwrite buffers
        __syncthreads();

        // ---- issue stage(t+1); latency hidden by other resident blocks ----
        if (t + 1 < nt) {
            const size_t joff = (size_t)(j0 + 64) * KDIM;
#pragma unroll
            for (int i = 0; i < 6; ++i) gload16((char*)sK + klds[i], ksrc[i] + joff);
#pragma unroll
            for (int i = 0; i < 4; ++i) gload16((char*)sV + vlds[i], vsrc[i] + j0 + 64);
        }
    }

    // ---- normalize + store ----
    const float invl = 1.0f / l_;
    _Float16* ob = attn + (size_t)qg * (NHEAD * VD) + h * VD + 4 * h5;
#pragma unroll
    for (int g = 0; g < 4; ++g) {
#pragma unroll
        for (int pp = 0; pp < 2; ++pp) {
            const int m = g * 4 + pp * 2;
            const int dof = pp * 2 + 8 * g;
            *reinterpret_cast<unsigned int*>(ob + dof) =
                pkh(o0[m] * invl, o0[m + 1] * invl);
            *reinterpret_cast<unsigned int*>(ob + 32 + dof) =
                pkh(o1[m] * invl, o1[m + 1] * invl);
            *reinterpret_cast<unsigned int*>(ob + 64 + dof) =
                pkh(o2[m] * invl, o2[m + 1] * invl);
            *reinterpret_cast<unsigned int*>(ob + 96 + dof) =
                pkh(o3[m] * invl, o3[m + 1] * invl);
        }
    }
}

// ---------------------------------------------------------------------------
extern "C" void kernel_launch(void* const* d_in, const int* in_sizes, int n_in,
                              void* d_out, int out_size, void* d_ws, size_t ws_size,
                              hipStream_t stream)
{
    (void)in_sizes; (void)n_in; (void)out_size; (void)ws_size;
    const float* x    = (const float*)d_in[0];
    const float* wqd  = (const float*)d_in[2];
    const float* wqu  = (const float*)d_in[3];
    const float* wqr  = (const float*)d_in[4];
    const float* wkvd = (const float*)d_in[5];
    const float* wkvu = (const float*)d_in[6];
    const float* wkr  = (const float*)d_in[7];
    const float* wout = (const float*)d_in[8];
    float* out = (float*)d_out;

    char* ws = (char*)d_ws;
    _Float16* x_h    = (_Float16*)ws; ws += (size_t)SEQ * EMBED * 2;
    _Float16* wdownh = (_Float16*)ws; ws += (size_t)1152 * EMBED * 2;
    _Float16* wquph  = (_Float16*)ws; ws += (size_t)3072 * QLR * 2;
    _Float16* wkvuh  = (_Float16*)ws; ws += (size_t)4096 * KVLR * 2;
    _Float16* c_q    = (_Float16*)ws; ws += (size_t)SEQ * QLR * 2;
    _Float16* c_kv   = (_Float16*)ws; ws += (size_t)SEQ * KVLR * 2;
    _Float16* ktmp   = (_Float16*)ws; ws += (size_t)SEQ * RD * 2;
    _Float16* qfin   = (_Float16*)ws; ws += (size_t)SEQ * NHEAD * KDIM * 2;
    _Float16* kfin   = (_Float16*)ws; ws += (size_t)SEQ * NHEAD * KDIM * 2;  // [h][s][192]
    _Float16* vT     = (_Float16*)ws; ws += (size_t)NHEAD * VD * SEQ * 2;    // [h*128+d][s]
    _Float16* attn   = x_h;      // alias (x_h dead after G1)
    _Float16* wouth  = c_q;      // alias (c_q dead after G2)

    dim3 blk(256);

    cvt_all<<<dim3(7040), blk, 0, stream>>>(x, wqd, wkvd, wkr, wqu, wqr, wkvu,
                                            x_h, wdownh, wquph, wkvuh);

    // G1: x @ [wqd;wkvd;wkr]^T -> c_q, c_kv, ktmp
    gemm_f16<0><<<dim3(9, 32), blk, 0, stream>>>(
        x_h, wdownh, c_q, c_kv, ktmp, nullptr, SEQ, 1152, EMBED);
    // G2: c_q @ [wqu;wqr]^T -> qfin
    gemm_f16<1><<<dim3(24, 32), blk, 0, stream>>>(
        c_q, wquph, qfin, nullptr, nullptr, nullptr, SEQ, 3072, QLR);
    // G3: c_kv @ wkvu^T -> kfin (per-head), vT
    gemm_f16<2><<<dim3(32, 32), blk, 0, stream>>>(
        c_kv, wkvuh, kfin, vT, nullptr, nullptr, SEQ, 4096, KVLR);

    cvt_plain<<<dim3(2048), blk, 0, stream>>>(wout, wouth, EMBED * EMBED / 8);

    rope_kernel<<<dim3(SEQ), blk, 0, stream>>>(qfin, kfin, ktmp);
    // attention: 512 blocks x 4 waves, 4 blocks/CU (single-buffered K+V)
    fattn<<<dim3(512), blk, 0, stream>>>(qfin, kfin, vT, attn);
    // G4: attn @ wout^T -> out (f32)
    gemm_f16<3><<<dim3(16, 32), blk, 0, stream>>>(
        attn, wouth, nullptr, nullptr, nullptr, out, SEQ, EMBED, NHEAD * VD);
}

// Round 17
// 337.225 us; speedup vs baseline: 1.8772x; 1.8772x over previous
//
#include <hip/hip_runtime.h>

// ---------------------------------------------------------------------------
// MLA forward, MI355X (gfx950). FP16 MFMA, f32 accumulate.
// SEQ=4096 EMBED=2048 H=16 QLR=512 KVLR=512 RD=64 VD=128 KD=192
// Round 17: r13/r15 base + conflict-free LDS permutation in fattn.
//   K slot: p = ((L ^ (r&7)) + 6*((r>>3)&3)) % 24  (rows 384B apart are
//   128B-congruent; the +6 rotation gives aliasing lanes distinct banks).
//   V slot: p = ((L ^ (r&7)) + 2*(r>>3)) & 7.
//   Applied both-sides: pre-permuted gload_lds source + matching reads.
// ---------------------------------------------------------------------------

#define SEQ   4096
#define EMBED 2048
#define NHEAD 16
#define QLR   512
#define KVLR  512
#define RD    64
#define VD    128
#define KDIM  192

typedef __attribute__((ext_vector_type(8)))  _Float16 half8;
typedef __attribute__((ext_vector_type(4)))  _Float16 half4;
typedef __attribute__((ext_vector_type(4)))  float    f32x4;
typedef __attribute__((ext_vector_type(16))) float    f32x16;
typedef __attribute__((ext_vector_type(2)))  unsigned int uint2v;
typedef __attribute__((ext_vector_type(4)))  unsigned int uint4v;

__device__ __forceinline__ void gload16(void* lds, const void* g) {
    __builtin_amdgcn_global_load_lds(
        (const __attribute__((address_space(1))) void*)g,
        (__attribute__((address_space(3))) void*)lds, 16, 0, 0);
}

__device__ __forceinline__ unsigned int pkh(float a, float b) {
    auto h = __builtin_amdgcn_cvt_pkrtz(a, b);   // __fp16 ext_vector(2)
    return __builtin_bit_cast(unsigned int, h);
}

__device__ __forceinline__ half8 cvt8(const float* p) {
    const float4 a = *reinterpret_cast<const float4*>(p);
    const float4 b = *reinterpret_cast<const float4*>(p + 4);
    half8 r;
    r[0] = (_Float16)a.x; r[1] = (_Float16)a.y; r[2] = (_Float16)a.z; r[3] = (_Float16)a.w;
    r[4] = (_Float16)b.x; r[5] = (_Float16)b.y; r[6] = (_Float16)b.z; r[7] = (_Float16)b.w;
    return r;
}

// ---------------- fused f32 -> f16 conversions (x, wdown, wqup, wkvu) ------
__global__ __launch_bounds__(256) void cvt_all(const float* __restrict__ x,
                                               const float* __restrict__ wqd,
                                               const float* __restrict__ wkvd,
                                               const float* __restrict__ wkr,
                                               const float* __restrict__ wqu,
                                               const float* __restrict__ wqr,
                                               const float* __restrict__ wkvu,
                                               _Float16* __restrict__ x_h,
                                               _Float16* __restrict__ wdownh,
                                               _Float16* __restrict__ wquph,
                                               _Float16* __restrict__ wkvuh)
{
    const int b = blockIdx.x;
    if (b < 4096) {
        const int i = b * 256 + threadIdx.x;
        reinterpret_cast<half8*>(x_h)[i] = cvt8(x + i * 8);
    } else if (b < 5248) {
        const int i = (b - 4096) * 256 + threadIdx.x;
        const int e = i * 8, row = e >> 11, col = e & 2047;
        const float* src = row < 512  ? wqd  + (size_t)row * 2048 + col
                         : row < 1024 ? wkvd + (size_t)(row - 512) * 2048 + col
                         : row < 1088 ? wkr  + (size_t)(row - 1024) * 2048 + col
                                      : nullptr;
        half8 r = {};
        if (src) r = cvt8(src);
        reinterpret_cast<half8*>(wdownh)[i] = r;
    } else if (b < 6016) {
        const int i = (b - 5248) * 256 + threadIdx.x;
        const int e = i * 8, row = e >> 9, col = e & 511;
        const float* src = row < 2048 ? wqu + (size_t)row * 512 + col
                                      : wqr + (size_t)(row - 2048) * 512 + col;
        reinterpret_cast<half8*>(wquph)[i] = cvt8(src);
    } else {
        const int i = (b - 6016) * 256 + threadIdx.x;
        reinterpret_cast<half8*>(wkvuh)[i] = cvt8(wkvu + i * 8);
    }
}

__global__ __launch_bounds__(256) void cvt_plain(const float* __restrict__ s,
                                                 _Float16* __restrict__ d, int n8) {
    const int i = blockIdx.x * 256 + threadIdx.x;
    if (i >= n8) return;
    reinterpret_cast<half8*>(d)[i] = cvt8(s + i * 8);
}

// ---------------------------------------------------------------------------
// f16 GEMM, m97 structure (r13 verbatim).
// ---------------------------------------------------------------------------
template <int EPI>
__global__ __launch_bounds__(256) void gemm_f16(const _Float16* __restrict__ A,
                                                const _Float16* __restrict__ B,
                                                _Float16* __restrict__ o0,
                                                _Float16* __restrict__ o1,
                                                _Float16* __restrict__ o2,
                                                float* __restrict__ of,
                                                int M, int N, int K)
{
    __shared__ _Float16 sA[128 * 64];
    __shared__ _Float16 sB[128 * 64];

    const int tid  = threadIdx.x;
    const int wid  = tid >> 6;
    const int lane = tid & 63;
    const int lr   = lane & 15;
    const int lg   = lane >> 4;
    const int row0 = blockIdx.y * 128;
    const int col0 = blockIdx.x * 128;
    const int war  = (wid >> 1) * 64;
    const int wac  = (wid & 1) * 64;

    const int sr = lane >> 3;
    const int sk = (lane & 7) * 8;
    const _Float16* Ab = A + (size_t)(row0 + wid * 8 + sr) * K + sk;
    const _Float16* Bb = B + (size_t)(col0 + wid * 8 + sr) * K + sk;

    f32x4 acc[4][4] = {};

    for (int k0 = 0; k0 < K; k0 += 64) {
#pragma unroll
        for (int i = 0; i < 4; ++i) {
            const int c = i * 4 + wid;
            gload16((char*)sA + c * 1024, Ab + (size_t)i * 32 * K + k0);
            gload16((char*)sB + c * 1024, Bb + (size_t)i * 32 * K + k0);
        }
        __syncthreads();

#pragma unroll
        for (int kk = 0; kk < 64; kk += 32) {
            half8 a[4], b[4];
#pragma unroll
            for (int i = 0; i < 4; ++i)
                a[i] = *reinterpret_cast<const half8*>(&sA[(war + i * 16 + lr) * 64 + kk + lg * 8]);
#pragma unroll
            for (int j = 0; j < 4; ++j)
                b[j] = *reinterpret_cast<const half8*>(&sB[(wac + j * 16 + lr) * 64 + kk + lg * 8]);
            __builtin_amdgcn_s_setprio(1);
#pragma unroll
            for (int i = 0; i < 4; ++i)
#pragma unroll
                for (int j = 0; j < 4; ++j)
                    acc[i][j] = __builtin_amdgcn_mfma_f32_16x16x32_f16(a[i], b[j], acc[i][j], 0, 0, 0);
            __builtin_amdgcn_s_setprio(0);
        }
        __syncthreads();
    }

#pragma unroll
    for (int i = 0; i < 4; ++i)
#pragma unroll
        for (int j = 0; j < 4; ++j) {
            const int grow0 = row0 + war + i * 16 + lg * 4;
            const int gcol  = col0 + wac + j * 16 + lr;
            if constexpr (EPI == 2) {
                if (gcol >= 2048) {
                    half4 pv;
#pragma unroll
                    for (int r = 0; r < 4; ++r) pv[r] = (_Float16)acc[i][j][r];
                    *reinterpret_cast<half4*>(&o1[(size_t)(gcol - 2048) * SEQ + grow0]) = pv;
                    continue;
                }
            }
#pragma unroll
            for (int r = 0; r < 4; ++r) {
                const int grow = grow0 + r;
                const float v = acc[i][j][r];
                if constexpr (EPI == 0) {
                    if (gcol < 512)       o0[(size_t)grow * 512 + gcol] = (_Float16)v;
                    else if (gcol < 1024) o1[(size_t)grow * 512 + gcol - 512] = (_Float16)v;
                    else if (gcol < 1088) o2[(size_t)grow * 64 + gcol - 1024] = (_Float16)v;
                } else if constexpr (EPI == 1) {
                    if (gcol < 2048)
                        o0[(size_t)grow * (NHEAD * KDIM) + (gcol >> 7) * KDIM + (gcol & 127)] = (_Float16)v;
                    else {
                        const int c = gcol - 2048;
                        o0[(size_t)grow * (NHEAD * KDIM) + (c >> 6) * KDIM + VD + (c & 63)] = (_Float16)v;
                    }
                } else if constexpr (EPI == 2) {
                    o0[((size_t)(gcol >> 7) * SEQ + grow) * KDIM + (gcol & 127)] = (_Float16)v;
                } else {
                    of[(size_t)grow * N + gcol] = v;
                }
            }
        }
}

// ---------------------------------------------------------------------------
// RoPE (standalone, r13 verbatim).
// ---------------------------------------------------------------------------
__global__ __launch_bounds__(256) void rope_kernel(_Float16* __restrict__ qf,
                                                   _Float16* __restrict__ kf,
                                                   const _Float16* __restrict__ ktmp)
{
    __shared__ float s_sin[32], s_cos[32];
    const int s   = blockIdx.x;
    const int tid = threadIdx.x;
    if (tid < 32) {
        const double inv = exp(-(double)tid * (log(10000.0) / 32.0));
        const double ang = (double)s * inv;
        s_sin[tid] = (float)sin(ang);
        s_cos[tid] = (float)cos(ang);
    }
    __syncthreads();

    for (int p = tid; p < NHEAD * 32; p += 256) {
        const int h = p >> 5, i = p & 31;
        const size_t base = (size_t)s * (NHEAD * KDIM) + h * KDIM + VD;
        const float x1 = (float)qf[base + i];
        const float x2 = (float)qf[base + 32 + i];
        const float cs = s_cos[i], sn = s_sin[i];
        qf[base + i]      = (_Float16)(x1 * cs - x2 * sn);
        qf[base + 32 + i] = (_Float16)(x2 * cs + x1 * sn);
    }
    if (tid < 32) {
        const int i = tid;
        const float x1 = (float)ktmp[(size_t)s * RD + i];
        const float x2 = (float)ktmp[(size_t)s * RD + 32 + i];
        const float cs = s_cos[i], sn = s_sin[i];
        const _Float16 r1 = (_Float16)(x1 * cs - x2 * sn);
        const _Float16 r2 = (_Float16)(x2 * cs + x1 * sn);
#pragma unroll
        for (int h = 0; h < NHEAD; ++h) {
            const size_t base = ((size_t)h * SEQ + s) * KDIM + VD;
            kf[base + i]      = r1;
            kf[base + 32 + i] = r2;
        }
    }
}

// ---------------------------------------------------------------------------
// Causal flash attention (r13 structure; conflict-free LDS permutation).
// 256 threads (4 waves), 128 q-cols/block. KV step 64. K dbuf 2x24KB,
// V single 16KB. K slot p=((L^(r&7))+6*((r>>3)&3))%24; V slot
// p=((L^(r&7))+2*(r>>3))&7 — aliasing lanes (r, r+8, r+16, r+24) now hit
// distinct bank groups. Sources pre-permuted for gload_lds (linear dest).
// ---------------------------------------------------------------------------
__global__ __launch_bounds__(256, 2) void fattn(const _Float16* __restrict__ qf,
                                                const _Float16* __restrict__ kf,
                                                const _Float16* __restrict__ vT,
                                                _Float16* __restrict__ attn)
{
    __shared__ _Float16 sK[2][64 * 192];   // 48 KB
    __shared__ _Float16 sV[128 * 64];      // 16 KB

    const int idx = blockIdx.x;
    const int h   = idx & 15;
    const int j   = idx >> 4;                              // 0..31
    const int qt  = (j < 16) ? (31 - 2 * j) : (2 * (j - 16));
    const int q0  = qt * 128;

    const int tid  = threadIdx.x;
    const int wid  = tid >> 6;
    const int lane = tid & 63;
    const int l31  = lane & 31;
    const int h5   = lane >> 5;
    const int x7   = l31 & 7;
    const int rotk = 6 * (l31 >> 3);       // K row-octet rotation (mod 24)
    const int rotv = 2 * (l31 >> 3);       // V row-octet rotation (mod 8)
    const int qg   = q0 + wid * 32 + l31;
    const int q0w  = q0 + wid * 32;

    const float scale = 0.0721687836487032f;   // 1/sqrt(192)

    // ---- K staging: slot p=gi%24 at row gi/24 holds L=((p-rot)%24)^(row&7)
    const _Float16* ksrc[6];
    int klds[6];
#pragma unroll
    for (int i = 0; i < 6; ++i) {
        const int c   = wid * 6 + i;
        const int gi  = c * 64 + lane;
        const int row = gi / 24;
        const int p   = gi % 24;
        const int rot = 6 * ((row >> 3) & 3);
        const int L   = ((p - rot + 24) % 24) ^ (row & 7);
        ksrc[i] = kf + ((size_t)h * SEQ + row) * KDIM + (L << 3);
        klds[i] = c * 1024;
    }
    // ---- V staging: slot s at row d holds L=((s-2*(d>>3))&7)^(d&7);
    //      d = c*8 + (lane>>3) so d>>3 = c, d&7 = lane>>3.
    const _Float16* vsrc[4];
    int vlds[4];
#pragma unroll
    for (int i = 0; i < 4; ++i) {
        const int c = wid * 4 + i;
        const int d = c * 8 + (lane >> 3);
        const int L = (((lane & 7) - 2 * (c & 3) + 8) & 7) ^ (lane >> 3);
        vsrc[i] = vT + ((size_t)h * VD + d) * SEQ + (L << 3);
        vlds[i] = c * 1024;
    }

    half8 qfr[12];
    {
        const _Float16* qb_ = qf + (size_t)qg * (NHEAD * KDIM) + h * KDIM + h5 * 8;
#pragma unroll
        for (int ks = 0; ks < 12; ++ks)
            qfr[ks] = *reinterpret_cast<const half8*>(qb_ + ks * 16);
    }

    f32x16 o0 = {}, o1 = {}, o2 = {}, o3 = {};
    float m_ = -1e30f, l_ = 0.0f;

    const int nt = 2 * qt + 2;

    // prologue: K[0] -> buf0, V[0]
#pragma unroll
    for (int i = 0; i < 6; ++i) gload16((char*)sK[0] + klds[i], ksrc[i]);
#pragma unroll
    for (int i = 0; i < 4; ++i) gload16((char*)sV + vlds[i], vsrc[i]);
    __syncthreads();

    int cur = 0;
    for (int t = 0; t < nt; ++t) {
        const int j0 = t * 64;

        // ---- issue K[t+1] into the other buffer ----
        if (t + 1 < nt) {
            const size_t joff = (size_t)(j0 + 64) * KDIM;
#pragma unroll
            for (int i = 0; i < 6; ++i)
                gload16((char*)sK[cur ^ 1] + klds[i], ksrc[i] + joff);
        }

        // ---- S^T = K · Q  (physical slot = ((L^x7)+rotk)%24) ----
        f32x16 s0 = {}, s1 = {};
        {
            const char* kb = (const char*)sK[cur];
            __builtin_amdgcn_s_setprio(1);
#pragma unroll
            for (int ks = 0; ks < 12; ++ks) {
                int pk = ((ks * 2 + h5) ^ x7) + rotk;
                pk = pk >= 24 ? pk - 24 : pk;
                const int go = pk << 4;
                const half8 ka = *reinterpret_cast<const half8*>(kb + l31 * 384 + go);
                const half8 kc = *reinterpret_cast<const half8*>(kb + (32 + l31) * 384 + go);
                s0 = __builtin_amdgcn_mfma_f32_32x32x16_f16(ka, qfr[ks], s0, 0, 0, 0);
                s1 = __builtin_amdgcn_mfma_f32_32x32x16_f16(kc, qfr[ks], s1, 0, 0, 0);
            }
            __builtin_amdgcn_s_setprio(0);
        }

        // ---- scale + causal mask ----
#pragma unroll
        for (int m = 0; m < 16; ++m) { s0[m] *= scale; s1[m] *= scale; }
        if (j0 + 63 > q0w) {
#pragma unroll
            for (int m = 0; m < 16; ++m) {
                const int kv = j0 + (m & 3) + 8 * (m >> 2) + 4 * h5;
                if (kv > qg)      s0[m] = -3.0e38f;
                if (kv + 32 > qg) s1[m] = -3.0e38f;
            }
        }

        // ---- row max ----
        float mx = s0[0];
#pragma unroll
        for (int m = 1; m < 16; ++m) mx = fmaxf(mx, s0[m]);
#pragma unroll
        for (int m = 0; m < 16; ++m) mx = fmaxf(mx, s1[m]);
        mx = fmaxf(mx, __shfl_xor(mx, 32, 64));

        // ---- defer-max online softmax ----
        if (!__all(mx - m_ <= 8.0f)) {
            const float mn = fmaxf(m_, mx);
            const float alpha = __expf(m_ - mn);
            m_ = mn;
            l_ *= alpha;
#pragma unroll
            for (int m = 0; m < 16; ++m) {
                o0[m] *= alpha; o1[m] *= alpha; o2[m] *= alpha; o3[m] *= alpha;
            }
        }
        float rs = 0.0f;
#pragma unroll
        for (int m = 0; m < 16; ++m) { const float p = __expf(s0[m] - m_); s0[m] = p; rs += p; }
#pragma unroll
        for (int m = 0; m < 16; ++m) { const float p = __expf(s1[m] - m_); s1[m] = p; rs += p; }
        rs += __shfl_xor(rs, 32, 64);
        l_ += rs;

        // ---- assemble P B-frags ----
        half8 pb0, pb1, pb2, pb3;
        {
            unsigned int x, x2, y, y2;
            x  = pkh(s0[0], s0[1]);  x2 = pkh(s0[2], s0[3]);
            y  = pkh(s0[4], s0[5]);  y2 = pkh(s0[6], s0[7]);
            uint2v r1 = __builtin_amdgcn_permlane32_swap(x, y, false, false);
            uint2v r2 = __builtin_amdgcn_permlane32_swap(x2, y2, false, false);
            { uint4v u = { r1[0], r2[0], r1[1], r2[1] }; pb0 = __builtin_bit_cast(half8, u); }
            x  = pkh(s0[8], s0[9]);  x2 = pkh(s0[10], s0[11]);
            y  = pkh(s0[12], s0[13]); y2 = pkh(s0[14], s0[15]);
            r1 = __builtin_amdgcn_permlane32_swap(x, y, false, false);
            r2 = __builtin_amdgcn_permlane32_swap(x2, y2, false, false);
            { uint4v u = { r1[0], r2[0], r1[1], r2[1] }; pb1 = __builtin_bit_cast(half8, u); }
            x  = pkh(s1[0], s1[1]);  x2 = pkh(s1[2], s1[3]);
            y  = pkh(s1[4], s1[5]);  y2 = pkh(s1[6], s1[7]);
            r1 = __builtin_amdgcn_permlane32_swap(x, y, false, false);
            r2 = __builtin_amdgcn_permlane32_swap(x2, y2, false, false);
            { uint4v u = { r1[0], r2[0], r1[1], r2[1] }; pb2 = __builtin_bit_cast(half8, u); }
            x  = pkh(s1[8], s1[9]);  x2 = pkh(s1[10], s1[11]);
            y  = pkh(s1[12], s1[13]); y2 = pkh(s1[14], s1[15]);
            r1 = __builtin_amdgcn_permlane32_swap(x, y, false, false);
            r2 = __builtin_amdgcn_permlane32_swap(x2, y2, false, false);
            { uint4v u = { r1[0], r2[0], r1[1], r2[1] }; pb3 = __builtin_bit_cast(half8, u); }
        }

        // barrier #1: V[t] (and K[t+1]) complete + all waves done reading K[cur]
        __syncthreads();

        // ---- O^T += V^T · P  (physical slot = ((L^x7)+rotv)&7) ----
        {
            const char* vbse = (const char*)sV;
            __builtin_amdgcn_s_setprio(1);
#pragma unroll
            for (int ks = 0; ks < 4; ++ks) {
                const int go = ((((ks * 2 + h5) ^ x7) + rotv) & 7) << 4;
                const half8 pbk = ks == 0 ? pb0 : ks == 1 ? pb1 : ks == 2 ? pb2 : pb3;
                const half8 v0 = *reinterpret_cast<const half8*>(vbse + (l31)      * 128 + go);
                const half8 v1 = *reinterpret_cast<const half8*>(vbse + (32 + l31) * 128 + go);
                const half8 v2 = *reinterpret_cast<const half8*>(vbse + (64 + l31) * 128 + go);
                const half8 v3 = *reinterpret_cast<const half8*>(vbse + (96 + l31) * 128 + go);
                o0 = __builtin_amdgcn_mfma_f32_32x32x16_f16(v0, pbk, o0, 0, 0, 0);
                o1 = __builtin_amdgcn_mfma_f32_32x32x16_f16(v1, pbk, o1, 0, 0, 0);
                o2 = __builtin_amdgcn_mfma_f32_32x32x16_f16(v2, pbk, o2, 0, 0, 0);
                o3 = __builtin_amdgcn_mfma_f32_32x32x16_f16(v3, pbk, o3, 0, 0, 0);
            }
            __builtin_amdgcn_s_setprio(0);
        }

        // barrier #2: all waves done reading V -> safe to overwrite
        __syncthreads();

        // ---- issue V[t+1] ----
        if (t + 1 < nt) {
            const int jn = j0 + 64;
#pragma unroll
            for (int i = 0; i < 4; ++i)
                gload16((char*)sV + vlds[i], vsrc[i] + jn);
        }
        cur ^= 1;
    }

    // ---- normalize + store ----
    const float invl = 1.0f / l_;
    _Float16* ob = attn + (size_t)qg * (NHEAD * VD) + h * VD + 4 * h5;
#pragma unroll
    for (int g = 0; g < 4; ++g) {
#pragma unroll
        for (int pp = 0; pp < 2; ++pp) {
            const int m = g * 4 + pp * 2;
            const int dof = pp * 2 + 8 * g;
            *reinterpret_cast<unsigned int*>(ob + dof) =
                pkh(o0[m] * invl, o0[m + 1] * invl);
            *reinterpret_cast<unsigned int*>(ob + 32 + dof) =
                pkh(o1[m] * invl, o1[m + 1] * invl);
            *reinterpret_cast<unsigned int*>(ob + 64 + dof) =
                pkh(o2[m] * invl, o2[m + 1] * invl);
            *reinterpret_cast<unsigned int*>(ob + 96 + dof) =
                pkh(o3[m] * invl, o3[m + 1] * invl);
        }
    }
}

// ---------------------------------------------------------------------------
extern "C" void kernel_launch(void* const* d_in, const int* in_sizes, int n_in,
                              void* d_out, int out_size, void* d_ws, size_t ws_size,
                              hipStream_t stream)
{
    (void)in_sizes; (void)n_in; (void)out_size; (void)ws_size;
    const float* x    = (const float*)d_in[0];
    const float* wqd  = (const float*)d_in[2];
    const float* wqu  = (const float*)d_in[3];
    const float* wqr  = (const float*)d_in[4];
    const float* wkvd = (const float*)d_in[5];
    const float* wkvu = (const float*)d_in[6];
    const float* wkr  = (const float*)d_in[7];
    const float* wout = (const float*)d_in[8];
    float* out = (float*)d_out;

    char* ws = (char*)d_ws;
    _Float16* x_h    = (_Float16*)ws; ws += (size_t)SEQ * EMBED * 2;
    _Float16* wdownh = (_Float16*)ws; ws += (size_t)1152 * EMBED * 2;
    _Float16* wquph  = (_Float16*)ws; ws += (size_t)3072 * QLR * 2;
    _Float16* wkvuh  = (_Float16*)ws; ws += (size_t)4096 * KVLR * 2;
    _Float16* c_q    = (_Float16*)ws; ws += (size_t)SEQ * QLR * 2;
    _Float16* c_kv   = (_Float16*)ws; ws += (size_t)SEQ * KVLR * 2;
    _Float16* ktmp   = (_Float16*)ws; ws += (size_t)SEQ * RD * 2;
    _Float16* qfin   = (_Float16*)ws; ws += (size_t)SEQ * NHEAD * KDIM * 2;
    _Float16* kfin   = (_Float16*)ws; ws += (size_t)SEQ * NHEAD * KDIM * 2;  // [h][s][192]
    _Float16* vT     = (_Float16*)ws; ws += (size_t)NHEAD * VD * SEQ * 2;    // [h*128+d][s]
    _Float16* attn   = x_h;      // alias (x_h dead after G1)
    _Float16* wouth  = c_q;      // alias (c_q dead after G2)

    dim3 blk(256);

    cvt_all<<<dim3(7040), blk, 0, stream>>>(x, wqd, wkvd, wkr, wqu, wqr, wkvu,
                                            x_h, wdownh, wquph, wkvuh);

    // G1: x @ [wqd;wkvd;wkr]^T -> c_q, c_kv, ktmp
    gemm_f16<0><<<dim3(9, 32), blk, 0, stream>>>(
        x_h, wdownh, c_q, c_kv, ktmp, nullptr, SEQ, 1152, EMBED);
    // G2: c_q @ [wqu;wqr]^T -> qfin
    gemm_f16<1><<<dim3(24, 32), blk, 0, stream>>>(
        c_q, wquph, qfin, nullptr, nullptr, nullptr, SEQ, 3072, QLR);
    // G3: c_kv @ wkvu^T -> kfin (per-head), vT
    gemm_f16<2><<<dim3(32, 32), blk, 0, stream>>>(
        c_kv, wkvuh, kfin, vT, nullptr, nullptr, SEQ, 4096, KVLR);

    cvt_plain<<<dim3(2048), blk, 0, stream>>>(wout, wouth, EMBED * EMBED / 8);

    rope_kernel<<<dim3(SEQ), blk, 0, stream>>>(qfin, kfin, ktmp);
    // attention: 512 blocks x 4 waves, conflict-free LDS permutation
    fattn<<<dim3(512), blk, 0, stream>>>(qfin, kfin, vT, attn);
    // G4: attn @ wout^T -> out (f32)
    gemm_f16<3><<<dim3(16, 32), blk, 0, stream>>>(
        attn, wouth, nullptr, nullptr, nullptr, out, SEQ, EMBED, NHEAD * VD);
}

// Round 18
// 327.711 us; speedup vs baseline: 1.9317x; 1.0290x over previous
//
#include <hip/hip_runtime.h>

// ---------------------------------------------------------------------------
// MLA forward, MI355X (gfx950). FP16 MFMA, f32 accumulate.
// SEQ=4096 EMBED=2048 H=16 QLR=512 KVLR=512 RD=64 VD=128 KD=192
// Round 18: consolidation at the measured optimum.
//   fattn  = r13 verbatim (syncthreads barriers, XOR swizzle — best: 164.5us)
//            minus the in-loop scale multiply (Q pre-scaled via weights).
//   cvt_all= r15 merge, with w_q_up/w_q_rope scaled by 1/sqrt(192) at
//            conversion time (qfin only feeds fattn; RoPE commutes).
// ---------------------------------------------------------------------------

#define SEQ   4096
#define EMBED 2048
#define NHEAD 16
#define QLR   512
#define KVLR  512
#define RD    64
#define VD    128
#define KDIM  192

#define SCALE_Q 0.0721687836487032f   // 1/sqrt(192), folded into w_q_up/rope

typedef __attribute__((ext_vector_type(8)))  _Float16 half8;
typedef __attribute__((ext_vector_type(4)))  _Float16 half4;
typedef __attribute__((ext_vector_type(4)))  float    f32x4;
typedef __attribute__((ext_vector_type(16))) float    f32x16;
typedef __attribute__((ext_vector_type(2)))  unsigned int uint2v;
typedef __attribute__((ext_vector_type(4)))  unsigned int uint4v;

__device__ __forceinline__ void gload16(void* lds, const void* g) {
    __builtin_amdgcn_global_load_lds(
        (const __attribute__((address_space(1))) void*)g,
        (__attribute__((address_space(3))) void*)lds, 16, 0, 0);
}

__device__ __forceinline__ unsigned int pkh(float a, float b) {
    auto h = __builtin_amdgcn_cvt_pkrtz(a, b);   // __fp16 ext_vector(2)
    return __builtin_bit_cast(unsigned int, h);
}

__device__ __forceinline__ half8 cvt8(const float* p) {
    const float4 a = *reinterpret_cast<const float4*>(p);
    const float4 b = *reinterpret_cast<const float4*>(p + 4);
    half8 r;
    r[0] = (_Float16)a.x; r[1] = (_Float16)a.y; r[2] = (_Float16)a.z; r[3] = (_Float16)a.w;
    r[4] = (_Float16)b.x; r[5] = (_Float16)b.y; r[6] = (_Float16)b.z; r[7] = (_Float16)b.w;
    return r;
}

__device__ __forceinline__ half8 cvt8s(const float* p, float s) {
    const float4 a = *reinterpret_cast<const float4*>(p);
    const float4 b = *reinterpret_cast<const float4*>(p + 4);
    half8 r;
    r[0] = (_Float16)(a.x * s); r[1] = (_Float16)(a.y * s);
    r[2] = (_Float16)(a.z * s); r[3] = (_Float16)(a.w * s);
    r[4] = (_Float16)(b.x * s); r[5] = (_Float16)(b.y * s);
    r[6] = (_Float16)(b.z * s); r[7] = (_Float16)(b.w * s);
    return r;
}

// ---------------- fused f32 -> f16 conversions (x, wdown, wqup, wkvu) ------
// wqup section is pre-scaled by 1/sqrt(192) (softmax scale folded into Q).
__global__ __launch_bounds__(256) void cvt_all(const float* __restrict__ x,
                                               const float* __restrict__ wqd,
                                               const float* __restrict__ wkvd,
                                               const float* __restrict__ wkr,
                                               const float* __restrict__ wqu,
                                               const float* __restrict__ wqr,
                                               const float* __restrict__ wkvu,
                                               _Float16* __restrict__ x_h,
                                               _Float16* __restrict__ wdownh,
                                               _Float16* __restrict__ wquph,
                                               _Float16* __restrict__ wkvuh)
{
    const int b = blockIdx.x;
    if (b < 4096) {
        const int i = b * 256 + threadIdx.x;
        reinterpret_cast<half8*>(x_h)[i] = cvt8(x + i * 8);
    } else if (b < 5248) {
        const int i = (b - 4096) * 256 + threadIdx.x;
        const int e = i * 8, row = e >> 11, col = e & 2047;
        const float* src = row < 512  ? wqd  + (size_t)row * 2048 + col
                         : row < 1024 ? wkvd + (size_t)(row - 512) * 2048 + col
                         : row < 1088 ? wkr  + (size_t)(row - 1024) * 2048 + col
                                      : nullptr;
        half8 r = {};
        if (src) r = cvt8(src);
        reinterpret_cast<half8*>(wdownh)[i] = r;
    } else if (b < 6016) {
        const int i = (b - 5248) * 256 + threadIdx.x;
        const int e = i * 8, row = e >> 9, col = e & 511;
        const float* src = row < 2048 ? wqu + (size_t)row * 512 + col
                                      : wqr + (size_t)(row - 2048) * 512 + col;
        reinterpret_cast<half8*>(wquph)[i] = cvt8s(src, SCALE_Q);
    } else {
        const int i = (b - 6016) * 256 + threadIdx.x;
        reinterpret_cast<half8*>(wkvuh)[i] = cvt8(wkvu + i * 8);
    }
}

__global__ __launch_bounds__(256) void cvt_plain(const float* __restrict__ s,
                                                 _Float16* __restrict__ d, int n8) {
    const int i = blockIdx.x * 256 + threadIdx.x;
    if (i >= n8) return;
    reinterpret_cast<half8*>(d)[i] = cvt8(s + i * 8);
}

// ---------------------------------------------------------------------------
// f16 GEMM, m97 structure (r13 verbatim).
// ---------------------------------------------------------------------------
template <int EPI>
__global__ __launch_bounds__(256) void gemm_f16(const _Float16* __restrict__ A,
                                                const _Float16* __restrict__ B,
                                                _Float16* __restrict__ o0,
                                                _Float16* __restrict__ o1,
                                                _Float16* __restrict__ o2,
                                                float* __restrict__ of,
                                                int M, int N, int K)
{
    __shared__ _Float16 sA[128 * 64];
    __shared__ _Float16 sB[128 * 64];

    const int tid  = threadIdx.x;
    const int wid  = tid >> 6;
    const int lane = tid & 63;
    const int lr   = lane & 15;
    const int lg   = lane >> 4;
    const int row0 = blockIdx.y * 128;
    const int col0 = blockIdx.x * 128;
    const int war  = (wid >> 1) * 64;
    const int wac  = (wid & 1) * 64;

    const int sr = lane >> 3;
    const int sk = (lane & 7) * 8;
    const _Float16* Ab = A + (size_t)(row0 + wid * 8 + sr) * K + sk;
    const _Float16* Bb = B + (size_t)(col0 + wid * 8 + sr) * K + sk;

    f32x4 acc[4][4] = {};

    for (int k0 = 0; k0 < K; k0 += 64) {
#pragma unroll
        for (int i = 0; i < 4; ++i) {
            const int c = i * 4 + wid;
            gload16((char*)sA + c * 1024, Ab + (size_t)i * 32 * K + k0);
            gload16((char*)sB + c * 1024, Bb + (size_t)i * 32 * K + k0);
        }
        __syncthreads();

#pragma unroll
        for (int kk = 0; kk < 64; kk += 32) {
            half8 a[4], b[4];
#pragma unroll
            for (int i = 0; i < 4; ++i)
                a[i] = *reinterpret_cast<const half8*>(&sA[(war + i * 16 + lr) * 64 + kk + lg * 8]);
#pragma unroll
            for (int j = 0; j < 4; ++j)
                b[j] = *reinterpret_cast<const half8*>(&sB[(wac + j * 16 + lr) * 64 + kk + lg * 8]);
            __builtin_amdgcn_s_setprio(1);
#pragma unroll
            for (int i = 0; i < 4; ++i)
#pragma unroll
                for (int j = 0; j < 4; ++j)
                    acc[i][j] = __builtin_amdgcn_mfma_f32_16x16x32_f16(a[i], b[j], acc[i][j], 0, 0, 0);
            __builtin_amdgcn_s_setprio(0);
        }
        __syncthreads();
    }

#pragma unroll
    for (int i = 0; i < 4; ++i)
#pragma unroll
        for (int j = 0; j < 4; ++j) {
            const int grow0 = row0 + war + i * 16 + lg * 4;
            const int gcol  = col0 + wac + j * 16 + lr;
            if constexpr (EPI == 2) {
                if (gcol >= 2048) {
                    half4 pv;
#pragma unroll
                    for (int r = 0; r < 4; ++r) pv[r] = (_Float16)acc[i][j][r];
                    *reinterpret_cast<half4*>(&o1[(size_t)(gcol - 2048) * SEQ + grow0]) = pv;
                    continue;
                }
            }
#pragma unroll
            for (int r = 0; r < 4; ++r) {
                const int grow = grow0 + r;
                const float v = acc[i][j][r];
                if constexpr (EPI == 0) {
                    if (gcol < 512)       o0[(size_t)grow * 512 + gcol] = (_Float16)v;
                    else if (gcol < 1024) o1[(size_t)grow * 512 + gcol - 512] = (_Float16)v;
                    else if (gcol < 1088) o2[(size_t)grow * 64 + gcol - 1024] = (_Float16)v;
                } else if constexpr (EPI == 1) {
                    if (gcol < 2048)
                        o0[(size_t)grow * (NHEAD * KDIM) + (gcol >> 7) * KDIM + (gcol & 127)] = (_Float16)v;
                    else {
                        const int c = gcol - 2048;
                        o0[(size_t)grow * (NHEAD * KDIM) + (c >> 6) * KDIM + VD + (c & 63)] = (_Float16)v;
                    }
                } else if constexpr (EPI == 2) {
                    o0[((size_t)(gcol >> 7) * SEQ + grow) * KDIM + (gcol & 127)] = (_Float16)v;
                } else {
                    of[(size_t)grow * N + gcol] = v;
                }
            }
        }
}

// ---------------------------------------------------------------------------
// RoPE (standalone; qfin values are pre-scaled — rotation commutes).
// ---------------------------------------------------------------------------
__global__ __launch_bounds__(256) void rope_kernel(_Float16* __restrict__ qf,
                                                   _Float16* __restrict__ kf,
                                                   const _Float16* __restrict__ ktmp)
{
    __shared__ float s_sin[32], s_cos[32];
    const int s   = blockIdx.x;
    const int tid = threadIdx.x;
    if (tid < 32) {
        const double inv = exp(-(double)tid * (log(10000.0) / 32.0));
        const double ang = (double)s * inv;
        s_sin[tid] = (float)sin(ang);
        s_cos[tid] = (float)cos(ang);
    }
    __syncthreads();

    for (int p = tid; p < NHEAD * 32; p += 256) {
        const int h = p >> 5, i = p & 31;
        const size_t base = (size_t)s * (NHEAD * KDIM) + h * KDIM + VD;
        const float x1 = (float)qf[base + i];
        const float x2 = (float)qf[base + 32 + i];
        const float cs = s_cos[i], sn = s_sin[i];
        qf[base + i]      = (_Float16)(x1 * cs - x2 * sn);
        qf[base + 32 + i] = (_Float16)(x2 * cs + x1 * sn);
    }
    if (tid < 32) {
        const int i = tid;
        const float x1 = (float)ktmp[(size_t)s * RD + i];
        const float x2 = (float)ktmp[(size_t)s * RD + 32 + i];
        const float cs = s_cos[i], sn = s_sin[i];
        const _Float16 r1 = (_Float16)(x1 * cs - x2 * sn);
        const _Float16 r2 = (_Float16)(x2 * cs + x1 * sn);
#pragma unroll
        for (int h = 0; h < NHEAD; ++h) {
            const size_t base = ((size_t)h * SEQ + s) * KDIM + VD;
            kf[base + i]      = r1;
            kf[base + 32 + i] = r2;
        }
    }
}

// ---------------------------------------------------------------------------
// Causal flash attention (r13 verbatim; Q pre-scaled so no in-loop scale).
// 256 threads (4 waves), 128 q-cols/block (32/wave). KV step 64.
// K dbuf (2x24 KB) + V single (16 KB), gload_lds with pre-swizzled (XOR)
// sources. All-register math: swapped QK^T (mfma_32x32x16), in-lane softmax
// + defer-max, P via cvt_pkrtz + permlane32_swap, O^T += V^T·P.
// Balanced qt pairing: qt = j<16 ? 31-2j : 2(j-16).
// ---------------------------------------------------------------------------
__global__ __launch_bounds__(256, 2) void fattn(const _Float16* __restrict__ qf,
                                                const _Float16* __restrict__ kf,
                                                const _Float16* __restrict__ vT,
                                                _Float16* __restrict__ attn)
{
    __shared__ _Float16 sK[2][64 * 192];   // 48 KB
    __shared__ _Float16 sV[128 * 64];      // 16 KB

    const int idx = blockIdx.x;
    const int h   = idx & 15;
    const int j   = idx >> 4;                              // 0..31
    const int qt  = (j < 16) ? (31 - 2 * j) : (2 * (j - 16));
    const int q0  = qt * 128;

    const int tid  = threadIdx.x;
    const int wid  = tid >> 6;
    const int lane = tid & 63;
    const int l31  = lane & 31;
    const int h5   = lane >> 5;
    const int x7   = l31 & 7;
    const int qg   = q0 + wid * 32 + l31;
    const int q0w  = q0 + wid * 32;

    const _Float16* ksrc[6];
    int klds[6];
#pragma unroll
    for (int i = 0; i < 6; ++i) {
        const int c   = wid * 6 + i;
        const int gi  = c * 64 + lane;
        const int row = gi / 24;
        const int g   = gi % 24;
        ksrc[i] = kf + ((size_t)h * SEQ + row) * KDIM + ((g ^ (row & 7)) << 3);
        klds[i] = c * 1024;
    }
    const _Float16* vsrc[4];
    int vlds[4];
#pragma unroll
    for (int i = 0; i < 4; ++i) {
        const int c = wid * 4 + i;
        const int d = c * 8 + (lane >> 3);
        vsrc[i] = vT + ((size_t)h * VD + d) * SEQ + (((lane & 7) ^ (lane >> 3)) << 3);
        vlds[i] = c * 1024;
    }

    half8 qfr[12];
    {
        const _Float16* qb_ = qf + (size_t)qg * (NHEAD * KDIM) + h * KDIM + h5 * 8;
#pragma unroll
        for (int ks = 0; ks < 12; ++ks)
            qfr[ks] = *reinterpret_cast<const half8*>(qb_ + ks * 16);
    }

    f32x16 o0 = {}, o1 = {}, o2 = {}, o3 = {};
    float m_ = -1e30f, l_ = 0.0f;

    const int nt = 2 * qt + 2;

    // prologue: K[0] -> buf0, V[0]
#pragma unroll
    for (int i = 0; i < 6; ++i) gload16((char*)sK[0] + klds[i], ksrc[i]);
#pragma unroll
    for (int i = 0; i < 4; ++i) gload16((char*)sV + vlds[i], vsrc[i]);
    __syncthreads();

    int cur = 0;
    for (int t = 0; t < nt; ++t) {
        const int j0 = t * 64;

        // ---- issue K[t+1] into the other buffer ----
        if (t + 1 < nt) {
            const size_t joff = (size_t)(j0 + 64) * KDIM;
#pragma unroll
            for (int i = 0; i < 6; ++i)
                gload16((char*)sK[cur ^ 1] + klds[i], ksrc[i] + joff);
        }

        // ---- S^T = K · Q  (Q pre-scaled; S already scaled) ----
        f32x16 s0 = {}, s1 = {};
        {
            const char* kb = (const char*)sK[cur];
            __builtin_amdgcn_s_setprio(1);
#pragma unroll
            for (int ks = 0; ks < 12; ++ks) {
                const int go = ((ks * 2 + h5) ^ x7) << 4;
                const half8 ka = *reinterpret_cast<const half8*>(kb + l31 * 384 + go);
                const half8 kc = *reinterpret_cast<const half8*>(kb + (32 + l31) * 384 + go);
                s0 = __builtin_amdgcn_mfma_f32_32x32x16_f16(ka, qfr[ks], s0, 0, 0, 0);
                s1 = __builtin_amdgcn_mfma_f32_32x32x16_f16(kc, qfr[ks], s1, 0, 0, 0);
            }
            __builtin_amdgcn_s_setprio(0);
        }

        // ---- causal mask ----
        if (j0 + 63 > q0w) {
#pragma unroll
            for (int m = 0; m < 16; ++m) {
                const int kv = j0 + (m & 3) + 8 * (m >> 2) + 4 * h5;
                if (kv > qg)      s0[m] = -3.0e38f;
                if (kv + 32 > qg) s1[m] = -3.0e38f;
            }
        }

        // ---- row max ----
        float mx = s0[0];
#pragma unroll
        for (int m = 1; m < 16; ++m) mx = fmaxf(mx, s0[m]);
#pragma unroll
        for (int m = 0; m < 16; ++m) mx = fmaxf(mx, s1[m]);
        mx = fmaxf(mx, __shfl_xor(mx, 32, 64));

        // ---- defer-max online softmax ----
        if (!__all(mx - m_ <= 8.0f)) {
            const float mn = fmaxf(m_, mx);
            const float alpha = __expf(m_ - mn);
            m_ = mn;
            l_ *= alpha;
#pragma unroll
            for (int m = 0; m < 16; ++m) {
                o0[m] *= alpha; o1[m] *= alpha; o2[m] *= alpha; o3[m] *= alpha;
            }
        }
        float rs = 0.0f;
#pragma unroll
        for (int m = 0; m < 16; ++m) { const float p = __expf(s0[m] - m_); s0[m] = p; rs += p; }
#pragma unroll
        for (int m = 0; m < 16; ++m) { const float p = __expf(s1[m] - m_); s1[m] = p; rs += p; }
        rs += __shfl_xor(rs, 32, 64);
        l_ += rs;

        // ---- assemble P B-frags ----
        half8 pb0, pb1, pb2, pb3;
        {
            unsigned int x, x2, y, y2;
            x  = pkh(s0[0], s0[1]);  x2 = pkh(s0[2], s0[3]);
            y  = pkh(s0[4], s0[5]);  y2 = pkh(s0[6], s0[7]);
            uint2v r1 = __builtin_amdgcn_permlane32_swap(x, y, false, false);
            uint2v r2 = __builtin_amdgcn_permlane32_swap(x2, y2, false, false);
            { uint4v u = { r1[0], r2[0], r1[1], r2[1] }; pb0 = __builtin_bit_cast(half8, u); }
            x  = pkh(s0[8], s0[9]);  x2 = pkh(s0[10], s0[11]);
            y  = pkh(s0[12], s0[13]); y2 = pkh(s0[14], s0[15]);
            r1 = __builtin_amdgcn_permlane32_swap(x, y, false, false);
            r2 = __builtin_amdgcn_permlane32_swap(x2, y2, false, false);
            { uint4v u = { r1[0], r2[0], r1[1], r2[1] }; pb1 = __builtin_bit_cast(half8, u); }
            x  = pkh(s1[0], s1[1]);  x2 = pkh(s1[2], s1[3]);
            y  = pkh(s1[4], s1[5]);  y2 = pkh(s1[6], s1[7]);
            r1 = __builtin_amdgcn_permlane32_swap(x, y, false, false);
            r2 = __builtin_amdgcn_permlane32_swap(x2, y2, false, false);
            { uint4v u = { r1[0], r2[0], r1[1], r2[1] }; pb2 = __builtin_bit_cast(half8, u); }
            x  = pkh(s1[8], s1[9]);  x2 = pkh(s1[10], s1[11]);
            y  = pkh(s1[12], s1[13]); y2 = pkh(s1[14], s1[15]);
            r1 = __builtin_amdgcn_permlane32_swap(x, y, false, false);
            r2 = __builtin_amdgcn_permlane32_swap(x2, y2, false, false);
            { uint4v u = { r1[0], r2[0], r1[1], r2[1] }; pb3 = __builtin_bit_cast(half8, u); }
        }

        // barrier #1: V[t] (and K[t+1]) complete + all waves done reading K[cur]
        __syncthreads();

        // ---- O^T += V^T · P ----
        {
            const char* vbse = (const char*)sV;
            __builtin_amdgcn_s_setprio(1);
#pragma unroll
            for (int ks = 0; ks < 4; ++ks) {
                const int go = ((ks * 2 + h5) ^ x7) << 4;
                const half8 pbk = ks == 0 ? pb0 : ks == 1 ? pb1 : ks == 2 ? pb2 : pb3;
                const half8 v0 = *reinterpret_cast<const half8*>(vbse + (l31)      * 128 + go);
                const half8 v1 = *reinterpret_cast<const half8*>(vbse + (32 + l31) * 128 + go);
                const half8 v2 = *reinterpret_cast<const half8*>(vbse + (64 + l31) * 128 + go);
                const half8 v3 = *reinterpret_cast<const half8*>(vbse + (96 + l31) * 128 + go);
                o0 = __builtin_amdgcn_mfma_f32_32x32x16_f16(v0, pbk, o0, 0, 0, 0);
                o1 = __builtin_amdgcn_mfma_f32_32x32x16_f16(v1, pbk, o1, 0, 0, 0);
                o2 = __builtin_amdgcn_mfma_f32_32x32x16_f16(v2, pbk, o2, 0, 0, 0);
                o3 = __builtin_amdgcn_mfma_f32_32x32x16_f16(v3, pbk, o3, 0, 0, 0);
            }
            __builtin_amdgcn_s_setprio(0);
        }

        // barrier #2: all waves done reading V -> safe to overwrite
        __syncthreads();

        // ---- issue V[t+1] ----
        if (t + 1 < nt) {
            const int jn = j0 + 64;
#pragma unroll
            for (int i = 0; i < 4; ++i)
                gload16((char*)sV + vlds[i], vsrc[i] + jn);
        }
        cur ^= 1;
    }

    // ---- normalize + store ----
    const float invl = 1.0f / l_;
    _Float16* ob = attn + (size_t)qg * (NHEAD * VD) + h * VD + 4 * h5;
#pragma unroll
    for (int g = 0; g < 4; ++g) {
#pragma unroll
        for (int pp = 0; pp < 2; ++pp) {
            const int m = g * 4 + pp * 2;
            const int dof = pp * 2 + 8 * g;
            *reinterpret_cast<unsigned int*>(ob + dof) =
                pkh(o0[m] * invl, o0[m + 1] * invl);
            *reinterpret_cast<unsigned int*>(ob + 32 + dof) =
                pkh(o1[m] * invl, o1[m + 1] * invl);
            *reinterpret_cast<unsigned int*>(ob + 64 + dof) =
                pkh(o2[m] * invl, o2[m + 1] * invl);
            *reinterpret_cast<unsigned int*>(ob + 96 + dof) =
                pkh(o3[m] * invl, o3[m + 1] * invl);
        }
    }
}

// ---------------------------------------------------------------------------
extern "C" void kernel_launch(void* const* d_in, const int* in_sizes, int n_in,
                              void* d_out, int out_size, void* d_ws, size_t ws_size,
                              hipStream_t stream)
{
    (void)in_sizes; (void)n_in; (void)out_size; (void)ws_size;
    const float* x    = (const float*)d_in[0];
    const float* wqd  = (const float*)d_in[2];
    const float* wqu  = (const float*)d_in[3];
    const float* wqr  = (const float*)d_in[4];
    const float* wkvd = (const float*)d_in[5];
    const float* wkvu = (const float*)d_in[6];
    const float* wkr  = (const float*)d_in[7];
    const float* wout = (const float*)d_in[8];
    float* out = (float*)d_out;

    char* ws = (char*)d_ws;
    _Float16* x_h    = (_Float16*)ws; ws += (size_t)SEQ * EMBED * 2;
    _Float16* wdownh = (_Float16*)ws; ws += (size_t)1152 * EMBED * 2;
    _Float16* wquph  = (_Float16*)ws; ws += (size_t)3072 * QLR * 2;
    _Float16* wkvuh  = (_Float16*)ws; ws += (size_t)4096 * KVLR * 2;
    _Float16* c_q    = (_Float16*)ws; ws += (size_t)SEQ * QLR * 2;
    _Float16* c_kv   = (_Float16*)ws; ws += (size_t)SEQ * KVLR * 2;
    _Float16* ktmp   = (_Float16*)ws; ws += (size_t)SEQ * RD * 2;
    _Float16* qfin   = (_Float16*)ws; ws += (size_t)SEQ * NHEAD * KDIM * 2;
    _Float16* kfin   = (_Float16*)ws; ws += (size_t)SEQ * NHEAD * KDIM * 2;  // [h][s][192]
    _Float16* vT     = (_Float16*)ws; ws += (size_t)NHEAD * VD * SEQ * 2;    // [h*128+d][s]
    _Float16* attn   = x_h;      // alias (x_h dead after G1)
    _Float16* wouth  = c_q;      // alias (c_q dead after G2)

    dim3 blk(256);

    cvt_all<<<dim3(7040), blk, 0, stream>>>(x, wqd, wkvd, wkr, wqu, wqr, wkvu,
                                            x_h, wdownh, wquph, wkvuh);

    // G1: x @ [wqd;wkvd;wkr]^T -> c_q, c_kv, ktmp
    gemm_f16<0><<<dim3(9, 32), blk, 0, stream>>>(
        x_h, wdownh, c_q, c_kv, ktmp, nullptr, SEQ, 1152, EMBED);
    // G2: c_q @ [wqu;wqr]^T -> qfin (pre-scaled by 1/sqrt(192) via weights)
    gemm_f16<1><<<dim3(24, 32), blk, 0, stream>>>(
        c_q, wquph, qfin, nullptr, nullptr, nullptr, SEQ, 3072, QLR);
    // G3: c_kv @ wkvu^T -> kfin (per-head), vT
    gemm_f16<2><<<dim3(32, 32), blk, 0, stream>>>(
        c_kv, wkvuh, kfin, vT, nullptr, nullptr, SEQ, 4096, KVLR);

    cvt_plain<<<dim3(2048), blk, 0, stream>>>(wout, wouth, EMBED * EMBED / 8);

    rope_kernel<<<dim3(SEQ), blk, 0, stream>>>(qfin, kfin, ktmp);
    // attention: 512 blocks x 4 waves, balanced qt pairing
    fattn<<<dim3(512), blk, 0, stream>>>(qfin, kfin, vT, attn);
    // G4: attn @ wout^T -> out (f32)
    gemm_f16<3><<<dim3(16, 32), blk, 0, stream>>>(
        attn, wouth, nullptr, nullptr, nullptr, out, SEQ, EMBED, NHEAD * VD);
}

// Round 19
// 323.626 us; speedup vs baseline: 1.9561x; 1.0126x over previous
//
#include <hip/hip_runtime.h>

// ---------------------------------------------------------------------------
// MLA forward, MI355X (gfx950). FP16 MFMA, f32 accumulate.
// SEQ=4096 EMBED=2048 H=16 QLR=512 KVLR=512 RD=64 VD=128 KD=192
// Round 19: the deconfounded TLP test. r18 base; fattn single-buffers K+V
//           (40 KB -> 4 blocks/CU) while KEEPING __launch_bounds__(256,2)
//           (the hint that yields 108 VGPR; r16 failed only because (256,4)
//           forced 64 VGPR and spilled). Same math, 2x block streams/CU.
// ---------------------------------------------------------------------------

#define SEQ   4096
#define EMBED 2048
#define NHEAD 16
#define QLR   512
#define KVLR  512
#define RD    64
#define VD    128
#define KDIM  192

#define SCALE_Q 0.0721687836487032f   // 1/sqrt(192), folded into w_q_up/rope

typedef __attribute__((ext_vector_type(8)))  _Float16 half8;
typedef __attribute__((ext_vector_type(4)))  _Float16 half4;
typedef __attribute__((ext_vector_type(4)))  float    f32x4;
typedef __attribute__((ext_vector_type(16))) float    f32x16;
typedef __attribute__((ext_vector_type(2)))  unsigned int uint2v;
typedef __attribute__((ext_vector_type(4)))  unsigned int uint4v;

__device__ __forceinline__ void gload16(void* lds, const void* g) {
    __builtin_amdgcn_global_load_lds(
        (const __attribute__((address_space(1))) void*)g,
        (__attribute__((address_space(3))) void*)lds, 16, 0, 0);
}

__device__ __forceinline__ unsigned int pkh(float a, float b) {
    auto h = __builtin_amdgcn_cvt_pkrtz(a, b);   // __fp16 ext_vector(2)
    return __builtin_bit_cast(unsigned int, h);
}

__device__ __forceinline__ half8 cvt8(const float* p) {
    const float4 a = *reinterpret_cast<const float4*>(p);
    const float4 b = *reinterpret_cast<const float4*>(p + 4);
    half8 r;
    r[0] = (_Float16)a.x; r[1] = (_Float16)a.y; r[2] = (_Float16)a.z; r[3] = (_Float16)a.w;
    r[4] = (_Float16)b.x; r[5] = (_Float16)b.y; r[6] = (_Float16)b.z; r[7] = (_Float16)b.w;
    return r;
}

__device__ __forceinline__ half8 cvt8s(const float* p, float s) {
    const float4 a = *reinterpret_cast<const float4*>(p);
    const float4 b = *reinterpret_cast<const float4*>(p + 4);
    half8 r;
    r[0] = (_Float16)(a.x * s); r[1] = (_Float16)(a.y * s);
    r[2] = (_Float16)(a.z * s); r[3] = (_Float16)(a.w * s);
    r[4] = (_Float16)(b.x * s); r[5] = (_Float16)(b.y * s);
    r[6] = (_Float16)(b.z * s); r[7] = (_Float16)(b.w * s);
    return r;
}

// ---------------- fused f32 -> f16 conversions (x, wdown, wqup, wkvu) ------
__global__ __launch_bounds__(256) void cvt_all(const float* __restrict__ x,
                                               const float* __restrict__ wqd,
                                               const float* __restrict__ wkvd,
                                               const float* __restrict__ wkr,
                                               const float* __restrict__ wqu,
                                               const float* __restrict__ wqr,
                                               const float* __restrict__ wkvu,
                                               _Float16* __restrict__ x_h,
                                               _Float16* __restrict__ wdownh,
                                               _Float16* __restrict__ wquph,
                                               _Float16* __restrict__ wkvuh)
{
    const int b = blockIdx.x;
    if (b < 4096) {
        const int i = b * 256 + threadIdx.x;
        reinterpret_cast<half8*>(x_h)[i] = cvt8(x + i * 8);
    } else if (b < 5248) {
        const int i = (b - 4096) * 256 + threadIdx.x;
        const int e = i * 8, row = e >> 11, col = e & 2047;
        const float* src = row < 512  ? wqd  + (size_t)row * 2048 + col
                         : row < 1024 ? wkvd + (size_t)(row - 512) * 2048 + col
                         : row < 1088 ? wkr  + (size_t)(row - 1024) * 2048 + col
                                      : nullptr;
        half8 r = {};
        if (src) r = cvt8(src);
        reinterpret_cast<half8*>(wdownh)[i] = r;
    } else if (b < 6016) {
        const int i = (b - 5248) * 256 + threadIdx.x;
        const int e = i * 8, row = e >> 9, col = e & 511;
        const float* src = row < 2048 ? wqu + (size_t)row * 512 + col
                                      : wqr + (size_t)(row - 2048) * 512 + col;
        reinterpret_cast<half8*>(wquph)[i] = cvt8s(src, SCALE_Q);
    } else {
        const int i = (b - 6016) * 256 + threadIdx.x;
        reinterpret_cast<half8*>(wkvuh)[i] = cvt8(wkvu + i * 8);
    }
}

__global__ __launch_bounds__(256) void cvt_plain(const float* __restrict__ s,
                                                 _Float16* __restrict__ d, int n8) {
    const int i = blockIdx.x * 256 + threadIdx.x;
    if (i >= n8) return;
    reinterpret_cast<half8*>(d)[i] = cvt8(s + i * 8);
}

// ---------------------------------------------------------------------------
// f16 GEMM, m97 structure (r13 verbatim).
// ---------------------------------------------------------------------------
template <int EPI>
__global__ __launch_bounds__(256) void gemm_f16(const _Float16* __restrict__ A,
                                                const _Float16* __restrict__ B,
                                                _Float16* __restrict__ o0,
                                                _Float16* __restrict__ o1,
                                                _Float16* __restrict__ o2,
                                                float* __restrict__ of,
                                                int M, int N, int K)
{
    __shared__ _Float16 sA[128 * 64];
    __shared__ _Float16 sB[128 * 64];

    const int tid  = threadIdx.x;
    const int wid  = tid >> 6;
    const int lane = tid & 63;
    const int lr   = lane & 15;
    const int lg   = lane >> 4;
    const int row0 = blockIdx.y * 128;
    const int col0 = blockIdx.x * 128;
    const int war  = (wid >> 1) * 64;
    const int wac  = (wid & 1) * 64;

    const int sr = lane >> 3;
    const int sk = (lane & 7) * 8;
    const _Float16* Ab = A + (size_t)(row0 + wid * 8 + sr) * K + sk;
    const _Float16* Bb = B + (size_t)(col0 + wid * 8 + sr) * K + sk;

    f32x4 acc[4][4] = {};

    for (int k0 = 0; k0 < K; k0 += 64) {
#pragma unroll
        for (int i = 0; i < 4; ++i) {
            const int c = i * 4 + wid;
            gload16((char*)sA + c * 1024, Ab + (size_t)i * 32 * K + k0);
            gload16((char*)sB + c * 1024, Bb + (size_t)i * 32 * K + k0);
        }
        __syncthreads();

#pragma unroll
        for (int kk = 0; kk < 64; kk += 32) {
            half8 a[4], b[4];
#pragma unroll
            for (int i = 0; i < 4; ++i)
                a[i] = *reinterpret_cast<const half8*>(&sA[(war + i * 16 + lr) * 64 + kk + lg * 8]);
#pragma unroll
            for (int j = 0; j < 4; ++j)
                b[j] = *reinterpret_cast<const half8*>(&sB[(wac + j * 16 + lr) * 64 + kk + lg * 8]);
            __builtin_amdgcn_s_setprio(1);
#pragma unroll
            for (int i = 0; i < 4; ++i)
#pragma unroll
                for (int j = 0; j < 4; ++j)
                    acc[i][j] = __builtin_amdgcn_mfma_f32_16x16x32_f16(a[i], b[j], acc[i][j], 0, 0, 0);
            __builtin_amdgcn_s_setprio(0);
        }
        __syncthreads();
    }

#pragma unroll
    for (int i = 0; i < 4; ++i)
#pragma unroll
        for (int j = 0; j < 4; ++j) {
            const int grow0 = row0 + war + i * 16 + lg * 4;
            const int gcol  = col0 + wac + j * 16 + lr;
            if constexpr (EPI == 2) {
                if (gcol >= 2048) {
                    half4 pv;
#pragma unroll
                    for (int r = 0; r < 4; ++r) pv[r] = (_Float16)acc[i][j][r];
                    *reinterpret_cast<half4*>(&o1[(size_t)(gcol - 2048) * SEQ + grow0]) = pv;
                    continue;
                }
            }
#pragma unroll
            for (int r = 0; r < 4; ++r) {
                const int grow = grow0 + r;
                const float v = acc[i][j][r];
                if constexpr (EPI == 0) {
                    if (gcol < 512)       o0[(size_t)grow * 512 + gcol] = (_Float16)v;
                    else if (gcol < 1024) o1[(size_t)grow * 512 + gcol - 512] = (_Float16)v;
                    else if (gcol < 1088) o2[(size_t)grow * 64 + gcol - 1024] = (_Float16)v;
                } else if constexpr (EPI == 1) {
                    if (gcol < 2048)
                        o0[(size_t)grow * (NHEAD * KDIM) + (gcol >> 7) * KDIM + (gcol & 127)] = (_Float16)v;
                    else {
                        const int c = gcol - 2048;
                        o0[(size_t)grow * (NHEAD * KDIM) + (c >> 6) * KDIM + VD + (c & 63)] = (_Float16)v;
                    }
                } else if constexpr (EPI == 2) {
                    o0[((size_t)(gcol >> 7) * SEQ + grow) * KDIM + (gcol & 127)] = (_Float16)v;
                } else {
                    of[(size_t)grow * N + gcol] = v;
                }
            }
        }
}

// ---------------------------------------------------------------------------
// RoPE (standalone; qfin values are pre-scaled — rotation commutes).
// ---------------------------------------------------------------------------
__global__ __launch_bounds__(256) void rope_kernel(_Float16* __restrict__ qf,
                                                   _Float16* __restrict__ kf,
                                                   const _Float16* __restrict__ ktmp)
{
    __shared__ float s_sin[32], s_cos[32];
    const int s   = blockIdx.x;
    const int tid = threadIdx.x;
    if (tid < 32) {
        const double inv = exp(-(double)tid * (log(10000.0) / 32.0));
        const double ang = (double)s * inv;
        s_sin[tid] = (float)sin(ang);
        s_cos[tid] = (float)cos(ang);
    }
    __syncthreads();

    for (int p = tid; p < NHEAD * 32; p += 256) {
        const int h = p >> 5, i = p & 31;
        const size_t base = (size_t)s * (NHEAD * KDIM) + h * KDIM + VD;
        const float x1 = (float)qf[base + i];
        const float x2 = (float)qf[base + 32 + i];
        const float cs = s_cos[i], sn = s_sin[i];
        qf[base + i]      = (_Float16)(x1 * cs - x2 * sn);
        qf[base + 32 + i] = (_Float16)(x2 * cs + x1 * sn);
    }
    if (tid < 32) {
        const int i = tid;
        const float x1 = (float)ktmp[(size_t)s * RD + i];
        const float x2 = (float)ktmp[(size_t)s * RD + 32 + i];
        const float cs = s_cos[i], sn = s_sin[i];
        const _Float16 r1 = (_Float16)(x1 * cs - x2 * sn);
        const _Float16 r2 = (_Float16)(x2 * cs + x1 * sn);
#pragma unroll
        for (int h = 0; h < NHEAD; ++h) {
            const size_t base = ((size_t)h * SEQ + s) * KDIM + VD;
            kf[base + i]      = r1;
            kf[base + 32 + i] = r2;
        }
    }
}

// ---------------------------------------------------------------------------
// Causal flash attention, TLP test (single-buffered K+V, 40 KB LDS ->
// 4 blocks/CU). __launch_bounds__(256,2) retained (gives 108 VGPR; actual
// occupancy = min(LDS=4, VGPR=4) blocks/CU). Per step:
//   bar(stage ready) -> QK -> softmax -> pack -> PV -> bar(reads done)
//   -> issue K[t+1], V[t+1] (latency covered by other resident blocks).
// All-register math identical to r18 (Q pre-scaled, no in-loop scale).
// ---------------------------------------------------------------------------
__global__ __launch_bounds__(256, 2) void fattn(const _Float16* __restrict__ qf,
                                                const _Float16* __restrict__ kf,
                                                const _Float16* __restrict__ vT,
                                                _Float16* __restrict__ attn)
{
    __shared__ _Float16 sK[64 * 192];   // 24 KB
    __shared__ _Float16 sV[128 * 64];   // 16 KB

    const int idx = blockIdx.x;
    const int h   = idx & 15;
    const int j   = idx >> 4;                              // 0..31
    const int qt  = (j < 16) ? (31 - 2 * j) : (2 * (j - 16));
    const int q0  = qt * 128;

    const int tid  = threadIdx.x;
    const int wid  = tid >> 6;
    const int lane = tid & 63;
    const int l31  = lane & 31;
    const int h5   = lane >> 5;
    const int x7   = l31 & 7;
    const int qg   = q0 + wid * 32 + l31;
    const int q0w  = q0 + wid * 32;

    const _Float16* ksrc[6];
    int klds[6];
#pragma unroll
    for (int i = 0; i < 6; ++i) {
        const int c   = wid * 6 + i;
        const int gi  = c * 64 + lane;
        const int row = gi / 24;
        const int g   = gi % 24;
        ksrc[i] = kf + ((size_t)h * SEQ + row) * KDIM + ((g ^ (row & 7)) << 3);
        klds[i] = c * 1024;
    }
    const _Float16* vsrc[4];
    int vlds[4];
#pragma unroll
    for (int i = 0; i < 4; ++i) {
        const int c = wid * 4 + i;
        const int d = c * 8 + (lane >> 3);
        vsrc[i] = vT + ((size_t)h * VD + d) * SEQ + (((lane & 7) ^ (lane >> 3)) << 3);
        vlds[i] = c * 1024;
    }

    half8 qfr[12];
    {
        const _Float16* qb_ = qf + (size_t)qg * (NHEAD * KDIM) + h * KDIM + h5 * 8;
#pragma unroll
        for (int ks = 0; ks < 12; ++ks)
            qfr[ks] = *reinterpret_cast<const half8*>(qb_ + ks * 16);
    }

    f32x16 o0 = {}, o1 = {}, o2 = {}, o3 = {};
    float m_ = -1e30f, l_ = 0.0f;

    const int nt = 2 * qt + 2;

    // prologue: stage tile 0
#pragma unroll
    for (int i = 0; i < 6; ++i) gload16((char*)sK + klds[i], ksrc[i]);
#pragma unroll
    for (int i = 0; i < 4; ++i) gload16((char*)sV + vlds[i], vsrc[i]);

    for (int t = 0; t < nt; ++t) {
        const int j0 = t * 64;

        // barrier #1: stage complete (syncthreads drains vmcnt)
        __syncthreads();

        // ---- S^T = K · Q  (S pre-scaled via Q) ----
        f32x16 s0 = {}, s1 = {};
        {
            const char* kb = (const char*)sK;
            __builtin_amdgcn_s_setprio(1);
#pragma unroll
            for (int ks = 0; ks < 12; ++ks) {
                const int go = ((ks * 2 + h5) ^ x7) << 4;
                const half8 ka = *reinterpret_cast<const half8*>(kb + l31 * 384 + go);
                const half8 kc = *reinterpret_cast<const half8*>(kb + (32 + l31) * 384 + go);
                s0 = __builtin_amdgcn_mfma_f32_32x32x16_f16(ka, qfr[ks], s0, 0, 0, 0);
                s1 = __builtin_amdgcn_mfma_f32_32x32x16_f16(kc, qfr[ks], s1, 0, 0, 0);
            }
            __builtin_amdgcn_s_setprio(0);
        }

        // ---- causal mask ----
        if (j0 + 63 > q0w) {
#pragma unroll
            for (int m = 0; m < 16; ++m) {
                const int kv = j0 + (m & 3) + 8 * (m >> 2) + 4 * h5;
                if (kv > qg)      s0[m] = -3.0e38f;
                if (kv + 32 > qg) s1[m] = -3.0e38f;
            }
        }

        // ---- row max ----
        float mx = s0[0];
#pragma unroll
        for (int m = 1; m < 16; ++m) mx = fmaxf(mx, s0[m]);
#pragma unroll
        for (int m = 0; m < 16; ++m) mx = fmaxf(mx, s1[m]);
        mx = fmaxf(mx, __shfl_xor(mx, 32, 64));

        // ---- defer-max online softmax ----
        if (!__all(mx - m_ <= 8.0f)) {
            const float mn = fmaxf(m_, mx);
            const float alpha = __expf(m_ - mn);
            m_ = mn;
            l_ *= alpha;
#pragma unroll
            for (int m = 0; m < 16; ++m) {
                o0[m] *= alpha; o1[m] *= alpha; o2[m] *= alpha; o3[m] *= alpha;
            }
        }
        float rs = 0.0f;
#pragma unroll
        for (int m = 0; m < 16; ++m) { const float p = __expf(s0[m] - m_); s0[m] = p; rs += p; }
#pragma unroll
        for (int m = 0; m < 16; ++m) { const float p = __expf(s1[m] - m_); s1[m] = p; rs += p; }
        rs += __shfl_xor(rs, 32, 64);
        l_ += rs;

        // ---- assemble P B-frags ----
        half8 pb0, pb1, pb2, pb3;
        {
            unsigned int x, x2, y, y2;
            x  = pkh(s0[0], s0[1]);  x2 = pkh(s0[2], s0[3]);
            y  = pkh(s0[4], s0[5]);  y2 = pkh(s0[6], s0[7]);
            uint2v r1 = __builtin_amdgcn_permlane32_swap(x, y, false, false);
            uint2v r2 = __builtin_amdgcn_permlane32_swap(x2, y2, false, false);
            { uint4v u = { r1[0], r2[0], r1[1], r2[1] }; pb0 = __builtin_bit_cast(half8, u); }
            x  = pkh(s0[8], s0[9]);  x2 = pkh(s0[10], s0[11]);
            y  = pkh(s0[12], s0[13]); y2 = pkh(s0[14], s0[15]);
            r1 = __builtin_amdgcn_permlane32_swap(x, y, false, false);
            r2 = __builtin_amdgcn_permlane32_swap(x2, y2, false, false);
            { uint4v u = { r1[0], r2[0], r1[1], r2[1] }; pb1 = __builtin_bit_cast(half8, u); }
            x  = pkh(s1[0], s1[1]);  x2 = pkh(s1[2], s1[3]);
            y  = pkh(s1[4], s1[5]);  y2 = pkh(s1[6], s1[7]);
            r1 = __builtin_amdgcn_permlane32_swap(x, y, false, false);
            r2 = __builtin_amdgcn_permlane32_swap(x2, y2, false, false);
            { uint4v u = { r1[0], r2[0], r1[1], r2[1] }; pb2 = __builtin_bit_cast(half8, u); }
            x  = pkh(s1[8], s1[9]);  x2 = pkh(s1[10], s1[11]);
            y  = pkh(s1[12], s1[13]); y2 = pkh(s1[14], s1[15]);
            r1 = __builtin_amdgcn_permlane32_swap(x, y, false, false);
            r2 = __builtin_amdgcn_permlane32_swap(x2, y2, false, false);
            { uint4v u = { r1[0], r2[0], r1[1], r2[1] }; pb3 = __builtin_bit_cast(half8, u); }
        }

        // ---- O^T += V^T · P ----
        {
            const char* vbse = (const char*)sV;
            __builtin_amdgcn_s_setprio(1);
#pragma unroll
            for (int ks = 0; ks < 4; ++ks) {
                const int go = ((ks * 2 + h5) ^ x7) << 4;
                const half8 pbk = ks == 0 ? pb0 : ks == 1 ? pb1 : ks == 2 ? pb2 : pb3;
                const half8 v0 = *reinterpret_cast<const half8*>(vbse + (l31)      * 128 + go);
                const half8 v1 = *reinterpret_cast<const half8*>(vbse + (32 + l31) * 128 + go);
                const half8 v2 = *reinterpret_cast<const half8*>(vbse + (64 + l31) * 128 + go);
                const half8 v3 = *reinterpret_cast<const half8*>(vbse + (96 + l31) * 128 + go);
                o0 = __builtin_amdgcn_mfma_f32_32x32x16_f16(v0, pbk, o0, 0, 0, 0);
                o1 = __builtin_amdgcn_mfma_f32_32x32x16_f16(v1, pbk, o1, 0, 0, 0);
                o2 = __builtin_amdgcn_mfma_f32_32x32x16_f16(v2, pbk, o2, 0, 0, 0);
                o3 = __builtin_amdgcn_mfma_f32_32x32x16_f16(v3, pbk, o3, 0, 0, 0);
            }
            __builtin_amdgcn_s_setprio(0);
        }

        // barrier #2: all reads done -> safe to overwrite buffers
        __syncthreads();

        // ---- issue stage(t+1); latency hidden by other resident blocks ----
        if (t + 1 < nt) {
            const size_t joff = (size_t)(j0 + 64) * KDIM;
#pragma unroll
            for (int i = 0; i < 6; ++i) gload16((char*)sK + klds[i], ksrc[i] + joff);
#pragma unroll
            for (int i = 0; i < 4; ++i) gload16((char*)sV + vlds[i], vsrc[i] + j0 + 64);
        }
    }

    // ---- normalize + store ----
    const float invl = 1.0f / l_;
    _Float16* ob = attn + (size_t)qg * (NHEAD * VD) + h * VD + 4 * h5;
#pragma unroll
    for (int g = 0; g < 4; ++g) {
#pragma unroll
        for (int pp = 0; pp < 2; ++pp) {
            const int m = g * 4 + pp * 2;
            const int dof = pp * 2 + 8 * g;
            *reinterpret_cast<unsigned int*>(ob + dof) =
                pkh(o0[m] * invl, o0[m + 1] * invl);
            *reinterpret_cast<unsigned int*>(ob + 32 + dof) =
                pkh(o1[m] * invl, o1[m + 1] * invl);
            *reinterpret_cast<unsigned int*>(ob + 64 + dof) =
                pkh(o2[m] * invl, o2[m + 1] * invl);
            *reinterpret_cast<unsigned int*>(ob + 96 + dof) =
                pkh(o3[m] * invl, o3[m + 1] * invl);
        }
    }
}

// ---------------------------------------------------------------------------
extern "C" void kernel_launch(void* const* d_in, const int* in_sizes, int n_in,
                              void* d_out, int out_size, void* d_ws, size_t ws_size,
                              hipStream_t stream)
{
    (void)in_sizes; (void)n_in; (void)out_size; (void)ws_size;
    const float* x    = (const float*)d_in[0];
    const float* wqd  = (const float*)d_in[2];
    const float* wqu  = (const float*)d_in[3];
    const float* wqr  = (const float*)d_in[4];
    const float* wkvd = (const float*)d_in[5];
    const float* wkvu = (const float*)d_in[6];
    const float* wkr  = (const float*)d_in[7];
    const float* wout = (const float*)d_in[8];
    float* out = (float*)d_out;

    char* ws = (char*)d_ws;
    _Float16* x_h    = (_Float16*)ws; ws += (size_t)SEQ * EMBED * 2;
    _Float16* wdownh = (_Float16*)ws; ws += (size_t)1152 * EMBED * 2;
    _Float16* wquph  = (_Float16*)ws; ws += (size_t)3072 * QLR * 2;
    _Float16* wkvuh  = (_Float16*)ws; ws += (size_t)4096 * KVLR * 2;
    _Float16* c_q    = (_Float16*)ws; ws += (size_t)SEQ * QLR * 2;
    _Float16* c_kv   = (_Float16*)ws; ws += (size_t)SEQ * KVLR * 2;
    _Float16* ktmp   = (_Float16*)ws; ws += (size_t)SEQ * RD * 2;
    _Float16* qfin   = (_Float16*)ws; ws += (size_t)SEQ * NHEAD * KDIM * 2;
    _Float16* kfin   = (_Float16*)ws; ws += (size_t)SEQ * NHEAD * KDIM * 2;  // [h][s][192]
    _Float16* vT     = (_Float16*)ws; ws += (size_t)NHEAD * VD * SEQ * 2;    // [h*128+d][s]
    _Float16* attn   = x_h;      // alias (x_h dead after G1)
    _Float16* wouth  = c_q;      // alias (c_q dead after G2)

    dim3 blk(256);

    cvt_all<<<dim3(7040), blk, 0, stream>>>(x, wqd, wkvd, wkr, wqu, wqr, wkvu,
                                            x_h, wdownh, wquph, wkvuh);

    // G1: x @ [wqd;wkvd;wkr]^T -> c_q, c_kv, ktmp
    gemm_f16<0><<<dim3(9, 32), blk, 0, stream>>>(
        x_h, wdownh, c_q, c_kv, ktmp, nullptr, SEQ, 1152, EMBED);
    // G2: c_q @ [wqu;wqr]^T -> qfin (pre-scaled by 1/sqrt(192) via weights)
    gemm_f16<1><<<dim3(24, 32), blk, 0, stream>>>(
        c_q, wquph, qfin, nullptr, nullptr, nullptr, SEQ, 3072, QLR);
    // G3: c_kv @ wkvu^T -> kfin (per-head), vT
    gemm_f16<2><<<dim3(32, 32), blk, 0, stream>>>(
        c_kv, wkvuh, kfin, vT, nullptr, nullptr, SEQ, 4096, KVLR);

    cvt_plain<<<dim3(2048), blk, 0, stream>>>(wout, wouth, EMBED * EMBED / 8);

    rope_kernel<<<dim3(SEQ), blk, 0, stream>>>(qfin, kfin, ktmp);
    // attention: 512 blocks x 4 waves, 4 blocks/CU (single-buffered K+V)
    fattn<<<dim3(512), blk, 0, stream>>>(qfin, kfin, vT, attn);
    // G4: attn @ wout^T -> out (f32)
    gemm_f16<3><<<dim3(16, 32), blk, 0, stream>>>(
        attn, wouth, nullptr, nullptr, nullptr, out, SEQ, EMBED, NHEAD * VD);
}